// Round 6
// baseline (170.357 us; speedup 1.0000x reference)
//
#include <hip/hip_runtime.h>
#include <hip/hip_bf16.h>
#include <type_traits>

typedef __bf16 bf16_t;
typedef __bf16 bf16x4 __attribute__((ext_vector_type(4)));
typedef __bf16 bf16x8 __attribute__((ext_vector_type(8)));
typedef float  f32x4  __attribute__((ext_vector_type(4)));

__device__ __forceinline__ f32x4 mfma16(bf16x8 a, bf16x8 b, f32x4 c) {
  return __builtin_amdgcn_mfma_f32_16x16x32_bf16(a, b, c, 0, 0, 0);
}

static constexpr int NB = 8;
static constexpr int LQ = 1024;
static constexpr int LKk = 1024;
static constexpr int DMODEL = 512;
static constexpr int NH = 8;
static constexpr int DKH = 64;
static constexpr int MROWS = NB * LQ;   // 8192
static constexpr int MWORDS = NB * LQ * (LKk / 64);  // 131072 u64 words

// swizzled byte offset for [R][128B] row-major LDS tiles (G4 XOR swizzle)
__device__ __forceinline__ int swz(int row, int byte) {
  return row * 128 + (byte ^ ((row & 7) << 4));
}

// ---------------- mask bit-pack: int32[..,64] -> u64 bitmask per 64 elems ----
// (identical to R2/R3's kernel, whose output was proven correct by absmax
//  equality with the direct-mask variants)
__global__ __launch_bounds__(256)
void mask_pack(const int* __restrict__ mask, unsigned long long* __restrict__ mpk) {
  const int l = threadIdx.x & 63;
  const int gw = (blockIdx.x * 256 + threadIdx.x) >> 6;
  const int nw = (gridDim.x * 256) >> 6;
  for (int wd = gw; wd < MWORDS; wd += nw) {
    int v = mask[(size_t)wd * 64 + l];
    unsigned long long bits = __ballot(v != 0);
    if (l == 0) mpk[wd] = bits;
  }
}

// C[M,N] = postscale * act(A[M,K] @ W[K,N] + bias)
template<int K, bool RELU, typename AT, typename OT>
__global__ __launch_bounds__(256)
void gemm_bias_act(const AT* __restrict__ A, const float* __restrict__ W,
                   const float* __restrict__ bias, OT* __restrict__ C, int N,
                   float postscale)
{
  __shared__ alignas(16) char Alds[64 * 128];
  __shared__ alignas(16) char Wlds[64 * 128];
  const int t = threadIdx.x;
  const int l = t & 63, w = t >> 6;
  const int m0 = blockIdx.y * 64, n0 = blockIdx.x * 64;

  f32x4 acc[4] = {};
  for (int k0 = 0; k0 < K; k0 += 64) {
    __syncthreads();
    {
      const int row = t >> 2, c0 = (t & 3) * 16;
      if constexpr (std::is_same<AT, float>::value) {
        const float4* ap = reinterpret_cast<const float4*>(A + (size_t)(m0 + row) * K + k0 + c0);
        #pragma unroll
        for (int j = 0; j < 4; ++j) {
          float4 f = ap[j];
          bf16x4 o = { (bf16_t)f.x, (bf16_t)f.y, (bf16_t)f.z, (bf16_t)f.w };
          *reinterpret_cast<bf16x4*>(&Alds[swz(row, (c0 + j * 4) * 2)]) = o;
        }
      } else {
        const bf16x8* ap = reinterpret_cast<const bf16x8*>(A + (size_t)(m0 + row) * K + k0 + c0);
        #pragma unroll
        for (int j = 0; j < 2; ++j)
          *reinterpret_cast<bf16x8*>(&Alds[swz(row, (c0 + j * 8) * 2)]) = ap[j];
      }
    }
    {
      const int k = t >> 2, nb = (t & 3) * 16;
      const float4* wp = reinterpret_cast<const float4*>(W + (size_t)(k0 + k) * N + n0 + nb);
      #pragma unroll
      for (int j = 0; j < 4; ++j) {
        float4 f = wp[j];
        float fv[4] = { f.x, f.y, f.z, f.w };
        #pragma unroll
        for (int i = 0; i < 4; ++i) {
          const int row = nb + j * 4 + i;
          *reinterpret_cast<bf16_t*>(&Wlds[swz(row, k * 2)]) = (bf16_t)fv[i];
        }
      }
    }
    __syncthreads();
    #pragma unroll
    for (int ks = 0; ks < 2; ++ks) {
      const int kb = (ks * 32 + ((l >> 4) * 8)) * 2;
      const int arow = w * 16 + (l & 15);
      bf16x8 af = *reinterpret_cast<const bf16x8*>(&Alds[swz(arow, kb)]);
      #pragma unroll
      for (int ct = 0; ct < 4; ++ct) {
        const int brow = ct * 16 + (l & 15);
        bf16x8 bfr = *reinterpret_cast<const bf16x8*>(&Wlds[swz(brow, kb)]);
        acc[ct] = mfma16(af, bfr, acc[ct]);
      }
    }
  }
  #pragma unroll
  for (int ct = 0; ct < 4; ++ct) {
    const int col = n0 + ct * 16 + (l & 15);
    const float bv = bias[col];
    #pragma unroll
    for (int r = 0; r < 4; ++r) {
      const int row = m0 + w * 16 + ((l >> 4) * 4) + r;
      float x = acc[ct][r] + bv;
      if constexpr (RELU) x = fmaxf(x, 0.f);
      C[(size_t)row * N + col] = (OT)(x * postscale);
    }
  }
}

// ---------------- flash attention: R1-verified structure + bitpacked mask ----
__global__ __launch_bounds__(256)
void attn_kernel(const bf16_t* __restrict__ Qp, const bf16_t* __restrict__ Kp,
                 const bf16_t* __restrict__ Vp, const unsigned long long* __restrict__ Mpk,
                 bf16_t* __restrict__ AO)
{
  __shared__ alignas(16) char Klds[64 * 128];       // [kv][d] row-major, swizzled
  __shared__ alignas(16) char Vlds[64 * 128];       // [d][kv] transposed, swizzled
  __shared__ alignas(16) char Plds[4 * 16 * 128];   // per-wave [16 q][64 kv], swizzled
  const int t = threadIdx.x, l = t & 63, w = t >> 6;
  const int bid = blockIdx.x;
  const int qt = bid & 15, h = (bid >> 4) & 7, b = bid >> 7;
  const int q0 = qt * 64;
  const size_t rb = (size_t)b * LQ;

  // Q fragments in registers (A layout: row = l&15, k = ks*32 + (l>>4)*8)
  bf16x8 qf[2];
  const int arow = q0 + w * 16 + (l & 15);
  #pragma unroll
  for (int ks = 0; ks < 2; ++ks)
    qf[ks] = *reinterpret_cast<const bf16x8*>(
        Qp + (rb + arow) * DMODEL + h * DKH + ks * 32 + (l >> 4) * 8);

  f32x4 acc[4] = {};
  float mrun[4], lsum[4];
  #pragma unroll
  for (int r = 0; r < 4; ++r) { mrun[r] = -1e30f; lsum[r] = 0.f; }

  for (int kv0 = 0; kv0 < LKk; kv0 += 64) {
    __syncthreads();
    // stage K tile [64 kv][64 d] (2 x 16B per thread)
    #pragma unroll
    for (int c = t * 2; c < t * 2 + 2; ++c) {
      const int row = c >> 3, cb = (c & 7) * 16;
      bf16x8 v = *reinterpret_cast<const bf16x8*>(
          Kp + (rb + kv0 + row) * DMODEL + h * DKH + cb / 2);
      *reinterpret_cast<bf16x8*>(&Klds[swz(row, cb)]) = v;
    }
    // stage V tile transposed: Vt[d][kv]  (R1-verified scalar writes)
    #pragma unroll
    for (int c = t * 2; c < t * 2 + 2; ++c) {
      const int kv = c >> 3, d0 = (c & 7) * 8;
      bf16x8 v = *reinterpret_cast<const bf16x8*>(
          Vp + (rb + kv0 + kv) * DMODEL + h * DKH + d0);
      #pragma unroll
      for (int i = 0; i < 8; ++i)
        *reinterpret_cast<bf16_t*>(&Vlds[swz(d0 + i, kv * 2)]) = v[i];
    }
    __syncthreads();

    // S = Q K^T  (B-frag reads K rows contiguously: B[d][kv] = K[kv][d])
    f32x4 s[4] = {};
    #pragma unroll
    for (int ks = 0; ks < 2; ++ks) {
      const int kb = (ks * 32 + (l >> 4) * 8) * 2;
      #pragma unroll
      for (int ct = 0; ct < 4; ++ct) {
        bf16x8 kf = *reinterpret_cast<const bf16x8*>(&Klds[swz(ct * 16 + (l & 15), kb)]);
        s[ct] = mfma16(qf[ks], kf, s[ct]);
      }
    }

    // mask (bitpacked) + online softmax (rows in 16-lane groups sharing l>>4)
    #pragma unroll
    for (int r = 0; r < 4; ++r) {
      const int q = q0 + w * 16 + (l >> 4) * 4 + r;
      const unsigned long long mword = Mpk[(size_t)(rb + q) * (LKk / 64) + (kv0 >> 6)];
      float sv[4], rmax = -1e30f;
      #pragma unroll
      for (int ct = 0; ct < 4; ++ct) {
        float x = s[ct][r];   // K pre-scaled by 1/sqrt(dk) in projection
        if (!((mword >> (ct * 16 + (l & 15))) & 1)) x = -1e8f;
        sv[ct] = x;
        rmax = fmaxf(rmax, x);
      }
      #pragma unroll
      for (int mm = 1; mm < 16; mm <<= 1) rmax = fmaxf(rmax, __shfl_xor(rmax, mm));
      const float newm = fmaxf(mrun[r], rmax);
      const float scale = __expf(mrun[r] - newm);
      #pragma unroll
      for (int dct = 0; dct < 4; ++dct) acc[dct][r] *= scale;
      float psum = 0.f;
      #pragma unroll
      for (int ct = 0; ct < 4; ++ct) {
        const float pv = __expf(sv[ct] - newm);
        sv[ct] = pv;
        psum += pv;
      }
      #pragma unroll
      for (int mm = 1; mm < 16; mm <<= 1) psum += __shfl_xor(psum, mm);
      lsum[r] = lsum[r] * scale + psum;
      mrun[r] = newm;
      const int prow = (l >> 4) * 4 + r;
      #pragma unroll
      for (int ct = 0; ct < 4; ++ct)
        *reinterpret_cast<bf16_t*>(
            &Plds[w * 2048 + swz(prow, (ct * 16 + (l & 15)) * 2)]) = (bf16_t)sv[ct];
    }

    // O += P V   (A-frag from Plds, B-frag from transposed Vlds)
    #pragma unroll
    for (int ks = 0; ks < 2; ++ks) {
      const int kb = (ks * 32 + (l >> 4) * 8) * 2;
      bf16x8 pf = *reinterpret_cast<const bf16x8*>(&Plds[w * 2048 + swz(l & 15, kb)]);
      #pragma unroll
      for (int dct = 0; dct < 4; ++dct) {
        bf16x8 vf = *reinterpret_cast<const bf16x8*>(&Vlds[swz(dct * 16 + (l & 15), kb)]);
        acc[dct] = mfma16(pf, vf, acc[dct]);
      }
    }
  }

  #pragma unroll
  for (int dct = 0; dct < 4; ++dct) {
    const int col = h * DKH + dct * 16 + (l & 15);
    #pragma unroll
    for (int r = 0; r < 4; ++r) {
      const int q = q0 + w * 16 + (l >> 4) * 4 + r;
      AO[(rb + q) * DMODEL + col] = (bf16_t)(acc[dct][r] / lsum[r]);
    }
  }
}

extern "C" void kernel_launch(void* const* d_in, const int* in_sizes, int n_in,
                              void* d_out, int out_size, void* d_ws, size_t ws_size,
                              hipStream_t stream)
{
  const float* query = (const float*)d_in[0];
  const float* keyin = (const float*)d_in[1];
  const int*   mask  = (const int*)d_in[2];
  const float* Wq = (const float*)d_in[3];
  const float* bq = (const float*)d_in[4];
  const float* Wk = (const float*)d_in[5];
  const float* bk = (const float*)d_in[6];
  const float* Wv = (const float*)d_in[7];
  const float* bv = (const float*)d_in[8];
  const float* Wo = (const float*)d_in[9];
  const float* bo = (const float*)d_in[10];
  float* out = (float*)d_out;

  bf16_t* Qp = (bf16_t*)d_ws;
  bf16_t* Kp = Qp + (size_t)MROWS * DMODEL;
  bf16_t* Vp = Kp + (size_t)MROWS * DMODEL;
  bf16_t* AO = Vp + (size_t)MROWS * DMODEL;
  unsigned long long* Mpk = (unsigned long long*)(AO + (size_t)MROWS * DMODEL);

  dim3 blk(256);
  dim3 gproj(DMODEL / 64, MROWS / 64);

  mask_pack<<<dim3(512), blk, 0, stream>>>(mask, Mpk);
  gemm_bias_act<256, true,  float,  bf16_t><<<gproj, blk, 0, stream>>>(query, Wq, bq, Qp, DMODEL, 1.0f);
  gemm_bias_act<256, true,  float,  bf16_t><<<gproj, blk, 0, stream>>>(keyin, Wk, bk, Kp, DMODEL, 0.125f);
  gemm_bias_act<256, true,  float,  bf16_t><<<gproj, blk, 0, stream>>>(keyin, Wv, bv, Vp, DMODEL, 1.0f);

  attn_kernel<<<dim3(NB * NH * (LQ / 64)), blk, 0, stream>>>(Qp, Kp, Vp, Mpk, AO);

  gemm_bias_act<512, false, bf16_t, float><<<gproj, blk, 0, stream>>>(AO, Wo, bo, out, DMODEL, 1.0f);
}

// Round 8
// 156.204 us; speedup vs baseline: 1.0906x; 1.0906x over previous
//
#include <hip/hip_runtime.h>
#include <hip/hip_bf16.h>
#include <type_traits>

typedef __bf16 bf16_t;
typedef __bf16 bf16x4 __attribute__((ext_vector_type(4)));
typedef __bf16 bf16x8 __attribute__((ext_vector_type(8)));
typedef float  f32x4  __attribute__((ext_vector_type(4)));

__device__ __forceinline__ f32x4 mfma16(bf16x8 a, bf16x8 b, f32x4 c) {
  return __builtin_amdgcn_mfma_f32_16x16x32_bf16(a, b, c, 0, 0, 0);
}

static constexpr int NB = 8;
static constexpr int LQ = 1024;
static constexpr int LKk = 1024;
static constexpr int DMODEL = 512;
static constexpr int NH = 8;
static constexpr int DKH = 64;
static constexpr int MROWS = NB * LQ;   // 8192
static constexpr int MWORDS = NB * LQ * (LKk / 64);  // 131072 u64 words

// swizzled byte offset for [R][128B] row-major LDS tiles (G4 XOR swizzle)
__device__ __forceinline__ int swz(int row, int byte) {
  return row * 128 + (byte ^ ((row & 7) << 4));
}

// ---------------- mask bit-pack: int32[..,64] -> u64 bitmask per 64 elems ----
// R6-verified logic; grid 512->4096 blocks (16384 waves x 8 words) to hide
// HBM latency on the load->ballot chain (was ~44us at 2 waves/SIMD).
__global__ __launch_bounds__(256)
void mask_pack(const int* __restrict__ mask, unsigned long long* __restrict__ mpk) {
  const int l = threadIdx.x & 63;
  const int gw = (blockIdx.x * 256 + threadIdx.x) >> 6;
  const int nw = (gridDim.x * 256) >> 6;
  for (int wd = gw; wd < MWORDS; wd += nw) {
    int v = mask[(size_t)wd * 64 + l];
    unsigned long long bits = __ballot(v != 0);
    if (l == 0) mpk[wd] = bits;
  }
}

// C[M,N] = postscale * act(A[M,K] @ W[K,N] + bias)
template<int K, bool RELU, typename AT, typename OT>
__global__ __launch_bounds__(256)
void gemm_bias_act(const AT* __restrict__ A, const float* __restrict__ W,
                   const float* __restrict__ bias, OT* __restrict__ C, int N,
                   float postscale)
{
  __shared__ alignas(16) char Alds[64 * 128];
  __shared__ alignas(16) char Wlds[64 * 128];
  const int t = threadIdx.x;
  const int l = t & 63, w = t >> 6;
  const int m0 = blockIdx.y * 64, n0 = blockIdx.x * 64;

  f32x4 acc[4] = {};
  for (int k0 = 0; k0 < K; k0 += 64) {
    __syncthreads();
    {
      const int row = t >> 2, c0 = (t & 3) * 16;
      if constexpr (std::is_same<AT, float>::value) {
        const float4* ap = reinterpret_cast<const float4*>(A + (size_t)(m0 + row) * K + k0 + c0);
        #pragma unroll
        for (int j = 0; j < 4; ++j) {
          float4 f = ap[j];
          bf16x4 o = { (bf16_t)f.x, (bf16_t)f.y, (bf16_t)f.z, (bf16_t)f.w };
          *reinterpret_cast<bf16x4*>(&Alds[swz(row, (c0 + j * 4) * 2)]) = o;
        }
      } else {
        const bf16x8* ap = reinterpret_cast<const bf16x8*>(A + (size_t)(m0 + row) * K + k0 + c0);
        #pragma unroll
        for (int j = 0; j < 2; ++j)
          *reinterpret_cast<bf16x8*>(&Alds[swz(row, (c0 + j * 8) * 2)]) = ap[j];
      }
    }
    {
      const int k = t >> 2, nb = (t & 3) * 16;
      const float4* wp = reinterpret_cast<const float4*>(W + (size_t)(k0 + k) * N + n0 + nb);
      #pragma unroll
      for (int j = 0; j < 4; ++j) {
        float4 f = wp[j];
        float fv[4] = { f.x, f.y, f.z, f.w };
        #pragma unroll
        for (int i = 0; i < 4; ++i) {
          const int row = nb + j * 4 + i;
          *reinterpret_cast<bf16_t*>(&Wlds[swz(row, k * 2)]) = (bf16_t)fv[i];
        }
      }
    }
    __syncthreads();
    #pragma unroll
    for (int ks = 0; ks < 2; ++ks) {
      const int kb = (ks * 32 + ((l >> 4) * 8)) * 2;
      const int arow = w * 16 + (l & 15);
      bf16x8 af = *reinterpret_cast<const bf16x8*>(&Alds[swz(arow, kb)]);
      #pragma unroll
      for (int ct = 0; ct < 4; ++ct) {
        const int brow = ct * 16 + (l & 15);
        bf16x8 bfr = *reinterpret_cast<const bf16x8*>(&Wlds[swz(brow, kb)]);
        acc[ct] = mfma16(af, bfr, acc[ct]);
      }
    }
  }
  #pragma unroll
  for (int ct = 0; ct < 4; ++ct) {
    const int col = n0 + ct * 16 + (l & 15);
    const float bv = bias[col];
    #pragma unroll
    for (int r = 0; r < 4; ++r) {
      const int row = m0 + w * 16 + ((l >> 4) * 4) + r;
      float x = acc[ct][r] + bv;
      if constexpr (RELU) x = fmaxf(x, 0.f);
      C[(size_t)row * N + col] = (OT)(x * postscale);
    }
  }
}

// ---------------- flash attention: R6-verified core + safe staging fixes -----
__global__ __launch_bounds__(256)
void attn_kernel(const bf16_t* __restrict__ Qp, const bf16_t* __restrict__ Kp,
                 const bf16_t* __restrict__ Vp, const unsigned long long* __restrict__ Mpk,
                 bf16_t* __restrict__ AO)
{
  __shared__ alignas(16) char Klds[64 * 128];       // [kv][d] row-major, swizzled
  __shared__ alignas(16) char Vlds[64 * 128];       // [d][kv] transposed, swizzled
  __shared__ alignas(16) char Plds[4 * 16 * 128];   // per-wave [16 q][64 kv], swizzled
  const int t = threadIdx.x, l = t & 63, w = t >> 6;
  // XCD-aware swizzle: XCD x = bid%8 owns 128 consecutive logical blocks =
  // one batch -> its K/V (4MB) stay in that XCD's L2. Bijective (1024 = 8*128).
  const int bid = (blockIdx.x & 7) * 128 + (blockIdx.x >> 3);
  const int qt = bid & 15, h = (bid >> 4) & 7, b = bid >> 7;
  const int q0 = qt * 64;
  const size_t rb = (size_t)b * LQ;

  // Q fragments in registers (A layout: row = l&15, k = ks*32 + (l>>4)*8)
  bf16x8 qf[2];
  const int arow = q0 + w * 16 + (l & 15);
  #pragma unroll
  for (int ks = 0; ks < 2; ++ks)
    qf[ks] = *reinterpret_cast<const bf16x8*>(
        Qp + (rb + arow) * DMODEL + h * DKH + ks * 32 + (l >> 4) * 8);

  f32x4 acc[4] = {};
  float mrun[4], lsum[4];
  #pragma unroll
  for (int r = 0; r < 4; ++r) { mrun[r] = -1e30f; lsum[r] = 0.f; }

  for (int kv0 = 0; kv0 < LKk; kv0 += 64) {
    // prefetch this tile's 4 mask words (read-only; hides under staging+MFMA)
    unsigned long long mw[4];
    #pragma unroll
    for (int r = 0; r < 4; ++r) {
      const int q = q0 + w * 16 + (l >> 4) * 4 + r;
      mw[r] = Mpk[(size_t)(rb + q) * (LKk / 64) + (kv0 >> 6)];
    }

    __syncthreads();
    // stage K tile [64 kv][64 d] (2 x 16B per thread)
    #pragma unroll
    for (int c = t * 2; c < t * 2 + 2; ++c) {
      const int row = c >> 3, cb = (c & 7) * 16;
      bf16x8 v = *reinterpret_cast<const bf16x8*>(
          Kp + (rb + kv0 + row) * DMODEL + h * DKH + cb / 2);
      *reinterpret_cast<bf16x8*>(&Klds[swz(row, cb)]) = v;
    }
    // stage V transposed: Vt[d][kv]. Scalar bf16 stores (R6-proven pattern),
    // thread remap kv = t&63 so each store instruction spans kv fully:
    // bank = (l>>1) ^ c -> 32 banks x 2 lanes = conflict-free (was 8-way).
    // Same byte image as R6; pure thread->element permutation.
    {
      const int kv = t & 63, d0 = (t >> 6) * 16;
      const bf16_t* s0 = Vp + (rb + kv0 + kv) * DMODEL + h * DKH + d0;
      bf16x8 v0 = *reinterpret_cast<const bf16x8*>(s0);
      bf16x8 v1 = *reinterpret_cast<const bf16x8*>(s0 + 8);
      #pragma unroll
      for (int i = 0; i < 8; ++i)
        *reinterpret_cast<bf16_t*>(&Vlds[swz(d0 + i, kv * 2)]) = v0[i];
      #pragma unroll
      for (int i = 0; i < 8; ++i)
        *reinterpret_cast<bf16_t*>(&Vlds[swz(d0 + 8 + i, kv * 2)]) = v1[i];
    }
    __syncthreads();

    // S = Q K^T  (B-frag reads K rows contiguously: B[d][kv] = K[kv][d])
    f32x4 s[4] = {};
    #pragma unroll
    for (int ks = 0; ks < 2; ++ks) {
      const int kb = (ks * 32 + (l >> 4) * 8) * 2;
      #pragma unroll
      for (int ct = 0; ct < 4; ++ct) {
        bf16x8 kf = *reinterpret_cast<const bf16x8*>(&Klds[swz(ct * 16 + (l & 15), kb)]);
        s[ct] = mfma16(qf[ks], kf, s[ct]);
      }
    }

    // mask (bitpacked, prefetched) + online softmax
    #pragma unroll
    for (int r = 0; r < 4; ++r) {
      const unsigned long long mword = mw[r];
      float sv[4], rmax = -1e30f;
      #pragma unroll
      for (int ct = 0; ct < 4; ++ct) {
        float x = s[ct][r];   // K pre-scaled by 1/sqrt(dk) in projection
        if (!((mword >> (ct * 16 + (l & 15))) & 1)) x = -1e8f;
        sv[ct] = x;
        rmax = fmaxf(rmax, x);
      }
      #pragma unroll
      for (int mm = 1; mm < 16; mm <<= 1) rmax = fmaxf(rmax, __shfl_xor(rmax, mm));
      const float newm = fmaxf(mrun[r], rmax);
      const float scale = __expf(mrun[r] - newm);
      #pragma unroll
      for (int dct = 0; dct < 4; ++dct) acc[dct][r] *= scale;
      float psum = 0.f;
      #pragma unroll
      for (int ct = 0; ct < 4; ++ct) {
        const float pv = __expf(sv[ct] - newm);
        sv[ct] = pv;
        psum += pv;
      }
      #pragma unroll
      for (int mm = 1; mm < 16; mm <<= 1) psum += __shfl_xor(psum, mm);
      lsum[r] = lsum[r] * scale + psum;
      mrun[r] = newm;
      const int prow = (l >> 4) * 4 + r;
      #pragma unroll
      for (int ct = 0; ct < 4; ++ct)
        *reinterpret_cast<bf16_t*>(
            &Plds[w * 2048 + swz(prow, (ct * 16 + (l & 15)) * 2)]) = (bf16_t)sv[ct];
    }

    // O += P V   (A-frag from Plds, B-frag from transposed Vlds)
    #pragma unroll
    for (int ks = 0; ks < 2; ++ks) {
      const int kb = (ks * 32 + (l >> 4) * 8) * 2;
      bf16x8 pf = *reinterpret_cast<const bf16x8*>(&Plds[w * 2048 + swz(l & 15, kb)]);
      #pragma unroll
      for (int dct = 0; dct < 4; ++dct) {
        bf16x8 vf = *reinterpret_cast<const bf16x8*>(&Vlds[swz(dct * 16 + (l & 15), kb)]);
        acc[dct] = mfma16(pf, vf, acc[dct]);
      }
    }
  }

  #pragma unroll
  for (int dct = 0; dct < 4; ++dct) {
    const int col = h * DKH + dct * 16 + (l & 15);
    #pragma unroll
    for (int r = 0; r < 4; ++r) {
      const int q = q0 + w * 16 + (l >> 4) * 4 + r;
      AO[(rb + q) * DMODEL + col] = (bf16_t)(acc[dct][r] / lsum[r]);
    }
  }
}

extern "C" void kernel_launch(void* const* d_in, const int* in_sizes, int n_in,
                              void* d_out, int out_size, void* d_ws, size_t ws_size,
                              hipStream_t stream)
{
  const float* query = (const float*)d_in[0];
  const float* keyin = (const float*)d_in[1];
  const int*   mask  = (const int*)d_in[2];
  const float* Wq = (const float*)d_in[3];
  const float* bq = (const float*)d_in[4];
  const float* Wk = (const float*)d_in[5];
  const float* bk = (const float*)d_in[6];
  const float* Wv = (const float*)d_in[7];
  const float* bv = (const float*)d_in[8];
  const float* Wo = (const float*)d_in[9];
  const float* bo = (const float*)d_in[10];
  float* out = (float*)d_out;

  bf16_t* Qp = (bf16_t*)d_ws;
  bf16_t* Kp = Qp + (size_t)MROWS * DMODEL;
  bf16_t* Vp = Kp + (size_t)MROWS * DMODEL;
  bf16_t* AO = Vp + (size_t)MROWS * DMODEL;
  unsigned long long* Mpk = (unsigned long long*)(AO + (size_t)MROWS * DMODEL);

  dim3 blk(256);
  dim3 gproj(DMODEL / 64, MROWS / 64);

  mask_pack<<<dim3(4096), blk, 0, stream>>>(mask, Mpk);
  gemm_bias_act<256, true,  float,  bf16_t><<<gproj, blk, 0, stream>>>(query, Wq, bq, Qp, DMODEL, 1.0f);
  gemm_bias_act<256, true,  float,  bf16_t><<<gproj, blk, 0, stream>>>(keyin, Wk, bk, Kp, DMODEL, 0.125f);
  gemm_bias_act<256, true,  float,  bf16_t><<<gproj, blk, 0, stream>>>(keyin, Wv, bv, Vp, DMODEL, 1.0f);

  attn_kernel<<<dim3(NB * NH * (LQ / 64)), blk, 0, stream>>>(Qp, Kp, Vp, Mpk, AO);

  gemm_bias_act<512, false, bf16_t, float><<<gproj, blk, 0, stream>>>(AO, Wo, bo, out, DMODEL, 1.0f);
}

// Round 9
// 135.751 us; speedup vs baseline: 1.2549x; 1.1507x over previous
//
#include <hip/hip_runtime.h>
#include <hip/hip_bf16.h>
#include <type_traits>

typedef __bf16 bf16_t;
typedef __bf16 bf16x4 __attribute__((ext_vector_type(4)));
typedef __bf16 bf16x8 __attribute__((ext_vector_type(8)));
typedef float  f32x4  __attribute__((ext_vector_type(4)));

__device__ __forceinline__ f32x4 mfma16(bf16x8 a, bf16x8 b, f32x4 c) {
  return __builtin_amdgcn_mfma_f32_16x16x32_bf16(a, b, c, 0, 0, 0);
}

static constexpr int NB = 8;
static constexpr int LQ = 1024;
static constexpr int LKk = 1024;
static constexpr int DMODEL = 512;
static constexpr int NH = 8;
static constexpr int DKH = 64;
static constexpr int MROWS = NB * LQ;   // 8192
static constexpr int MWORDS = NB * LQ * (LKk / 64);  // 131072 u64 words

// swizzled byte offset for [R][128B] row-major LDS tiles (G4 XOR swizzle)
__device__ __forceinline__ int swz(int row, int byte) {
  return row * 128 + (byte ^ ((row & 7) << 4));
}

// ---------------- mask bit-pack: int32[..,64] -> u64 bitmask per 64 elems ----
__global__ __launch_bounds__(256)
void mask_pack(const int* __restrict__ mask, unsigned long long* __restrict__ mpk) {
  const int l = threadIdx.x & 63;
  const int gw = (blockIdx.x * 256 + threadIdx.x) >> 6;
  const int nw = (gridDim.x * 256) >> 6;
  for (int wd = gw; wd < MWORDS; wd += nw) {
    int v = mask[(size_t)wd * 64 + l];
    unsigned long long bits = __ballot(v != 0);
    if (l == 0) mpk[wd] = bits;
  }
}

// C[M,N] = postscale * act(A[M,K] @ W[K,N] + bias)
template<int K, bool RELU, typename AT, typename OT>
__global__ __launch_bounds__(256)
void gemm_bias_act(const AT* __restrict__ A, const float* __restrict__ W,
                   const float* __restrict__ bias, OT* __restrict__ C, int N,
                   float postscale)
{
  __shared__ alignas(16) char Alds[64 * 128];
  __shared__ alignas(16) char Wlds[64 * 128];
  const int t = threadIdx.x;
  const int l = t & 63, w = t >> 6;
  const int m0 = blockIdx.y * 64, n0 = blockIdx.x * 64;

  f32x4 acc[4] = {};
  for (int k0 = 0; k0 < K; k0 += 64) {
    __syncthreads();
    {
      const int row = t >> 2, c0 = (t & 3) * 16;
      if constexpr (std::is_same<AT, float>::value) {
        const float4* ap = reinterpret_cast<const float4*>(A + (size_t)(m0 + row) * K + k0 + c0);
        #pragma unroll
        for (int j = 0; j < 4; ++j) {
          float4 f = ap[j];
          bf16x4 o = { (bf16_t)f.x, (bf16_t)f.y, (bf16_t)f.z, (bf16_t)f.w };
          *reinterpret_cast<bf16x4*>(&Alds[swz(row, (c0 + j * 4) * 2)]) = o;
        }
      } else {
        const bf16x8* ap = reinterpret_cast<const bf16x8*>(A + (size_t)(m0 + row) * K + k0 + c0);
        #pragma unroll
        for (int j = 0; j < 2; ++j)
          *reinterpret_cast<bf16x8*>(&Alds[swz(row, (c0 + j * 8) * 2)]) = ap[j];
      }
    }
    {
      const int k = t >> 2, nb = (t & 3) * 16;
      const float4* wp = reinterpret_cast<const float4*>(W + (size_t)(k0 + k) * N + n0 + nb);
      #pragma unroll
      for (int j = 0; j < 4; ++j) {
        float4 f = wp[j];
        float fv[4] = { f.x, f.y, f.z, f.w };
        #pragma unroll
        for (int i = 0; i < 4; ++i) {
          const int row = nb + j * 4 + i;
          *reinterpret_cast<bf16_t*>(&Wlds[swz(row, k * 2)]) = (bf16_t)fv[i];
        }
      }
    }
    __syncthreads();
    #pragma unroll
    for (int ks = 0; ks < 2; ++ks) {
      const int kb = (ks * 32 + ((l >> 4) * 8)) * 2;
      const int arow = w * 16 + (l & 15);
      bf16x8 af = *reinterpret_cast<const bf16x8*>(&Alds[swz(arow, kb)]);
      #pragma unroll
      for (int ct = 0; ct < 4; ++ct) {
        const int brow = ct * 16 + (l & 15);
        bf16x8 bfr = *reinterpret_cast<const bf16x8*>(&Wlds[swz(brow, kb)]);
        acc[ct] = mfma16(af, bfr, acc[ct]);
      }
    }
  }
  #pragma unroll
  for (int ct = 0; ct < 4; ++ct) {
    const int col = n0 + ct * 16 + (l & 15);
    const float bv = bias[col];
    #pragma unroll
    for (int r = 0; r < 4; ++r) {
      const int row = m0 + w * 16 + ((l >> 4) * 4) + r;
      float x = acc[ct][r] + bv;
      if constexpr (RELU) x = fmaxf(x, 0.f);
      C[(size_t)row * N + col] = (OT)(x * postscale);
    }
  }
}

// ------- flash attention: swapped QK^T, lane-parallel softmax, R8 chassis ----
__global__ __launch_bounds__(256)
void attn_kernel(const bf16_t* __restrict__ Qp, const bf16_t* __restrict__ Kp,
                 const bf16_t* __restrict__ Vp, const unsigned long long* __restrict__ Mpk,
                 bf16_t* __restrict__ AO)
{
  __shared__ alignas(16) char Klds[64 * 128];       // [kv][d] row-major, swizzled
  __shared__ alignas(16) char Vlds[64 * 128];       // [d][kv] transposed, swizzled
  __shared__ alignas(16) char Plds[4 * 16 * 128];   // per-wave [16 q][64 kv], swizzled
  const int t = threadIdx.x, l = t & 63, w = t >> 6;
  const int g = l >> 4, qh = l & 15;
  // XCD-aware swizzle (R8-proven): XCD x = bid%8 owns one batch.
  const int bid = (blockIdx.x & 7) * 128 + (blockIdx.x >> 3);
  const int qt = bid & 15, h = (bid >> 4) & 7, b = bid >> 7;
  const int q0 = qt * 64 + w * 16;   // this wave's 16 q rows
  const size_t rb = (size_t)b * LQ;

  // Q B-frag: lane (n=q=qh) provides B[k=d][q]; K pre-scaled by 1/8 in proj.
  bf16x8 qf[2];
  #pragma unroll
  for (int ks = 0; ks < 2; ++ks)
    qf[ks] = *reinterpret_cast<const bf16x8*>(
        Qp + (rb + q0 + qh) * DMODEL + h * DKH + ks * 32 + g * 8);

  const unsigned long long* mrow = Mpk + (rb + q0 + qh) * (LKk / 64);

  f32x4 acc[4] = {};                 // acc[dct][r] = O[q=g*4+r][d=dct*16+qh]
  float mrun = -1e30f, lsum = 0.f;   // softmax state for q = qh (x4 g-replicas)

  for (int kv0 = 0; kv0 < LKk; kv0 += 64) {
    // prefetch this tile's mask word (1 u64 per lane)
    const unsigned long long mword = mrow[kv0 >> 6];

    __syncthreads();
    // stage K tile [64 kv][64 d] (2 x 16B per thread) — R8-proven
    #pragma unroll
    for (int c = t * 2; c < t * 2 + 2; ++c) {
      const int row = c >> 3, cb = (c & 7) * 16;
      bf16x8 v = *reinterpret_cast<const bf16x8*>(
          Kp + (rb + kv0 + row) * DMODEL + h * DKH + cb / 2);
      *reinterpret_cast<bf16x8*>(&Klds[swz(row, cb)]) = v;
    }
    // stage V transposed: Vt[d][kv], scalar bf16 stores, conflict-free remap
    // (R8-proven byte image + thread mapping)
    {
      const int kv = t & 63, d0 = (t >> 6) * 16;
      const bf16_t* s0 = Vp + (rb + kv0 + kv) * DMODEL + h * DKH + d0;
      bf16x8 v0 = *reinterpret_cast<const bf16x8*>(s0);
      bf16x8 v1 = *reinterpret_cast<const bf16x8*>(s0 + 8);
      #pragma unroll
      for (int i = 0; i < 8; ++i)
        *reinterpret_cast<bf16_t*>(&Vlds[swz(d0 + i, kv * 2)]) = v0[i];
      #pragma unroll
      for (int i = 0; i < 8; ++i)
        *reinterpret_cast<bf16_t*>(&Vlds[swz(d0 + 8 + i, kv * 2)]) = v1[i];
    }
    __syncthreads();

    // S^T = mfma(A=K, B=Q): D[m=kv][n=q]; lane holds kv = ct*16+g*4+r, q = qh
    f32x4 s[4] = {};
    #pragma unroll
    for (int ks = 0; ks < 2; ++ks) {
      const int kb = (ks * 32 + g * 8) * 2;
      #pragma unroll
      for (int ct = 0; ct < 4; ++ct) {
        bf16x8 kf = *reinterpret_cast<const bf16x8*>(&Klds[swz(ct * 16 + qh, kb)]);
        s[ct] = mfma16(kf, qf[ks], s[ct]);
      }
    }

    // mask + lane-parallel online softmax (single pass over 16 values)
    float p[4][4];
    float rmax = -1e30f;
    #pragma unroll
    for (int ct = 0; ct < 4; ++ct) {
      #pragma unroll
      for (int r = 0; r < 4; ++r) {
        float x = ((mword >> (ct * 16 + g * 4 + r)) & 1) ? s[ct][r] : -1e8f;
        p[ct][r] = x;
        rmax = fmaxf(rmax, x);
      }
    }
    rmax = fmaxf(rmax, __shfl_xor(rmax, 16));
    rmax = fmaxf(rmax, __shfl_xor(rmax, 32));
    const float newm = fmaxf(mrun, rmax);
    const float scale = __expf(mrun - newm);
    mrun = newm;

    float psum = 0.f;
    #pragma unroll
    for (int ct = 0; ct < 4; ++ct) {
      #pragma unroll
      for (int r = 0; r < 4; ++r) {
        p[ct][r] = __expf(p[ct][r] - newm);
        psum += p[ct][r];
      }
    }
    psum += __shfl_xor(psum, 16);
    psum += __shfl_xor(psum, 32);
    lsum = lsum * scale + psum;

    // unconditional O rescale (scale of q-row g*4+r lives at lane g*4+r,
    // state identical across g-replicas after the reduces)
    #pragma unroll
    for (int r = 0; r < 4; ++r) {
      const float sr = __shfl(scale, g * 4 + r, 64);
      #pragma unroll
      for (int dct = 0; dct < 4; ++dct) acc[dct][r] *= sr;
    }

    // write P[q=qh][kv=ct*16+g*4+r] to per-wave LDS — SCALAR bf16 stores only
    // (packed-u32 stores to swizzled LDS are the R2-R7 curse; forbidden)
    #pragma unroll
    for (int ct = 0; ct < 4; ++ct) {
      #pragma unroll
      for (int r = 0; r < 4; ++r)
        *reinterpret_cast<bf16_t*>(
            &Plds[w * 2048 + swz(qh, (ct * 16 + g * 4 + r) * 2)]) = (bf16_t)p[ct][r];
    }

    // O += P V   (A-frag rows q from Plds, B-frag from transposed Vlds)
    #pragma unroll
    for (int ks = 0; ks < 2; ++ks) {
      const int kb = (ks * 32 + g * 8) * 2;
      bf16x8 pf = *reinterpret_cast<const bf16x8*>(&Plds[w * 2048 + swz(qh, kb)]);
      #pragma unroll
      for (int dct = 0; dct < 4; ++dct) {
        bf16x8 vf = *reinterpret_cast<const bf16x8*>(&Vlds[swz(dct * 16 + qh, kb)]);
        acc[dct] = mfma16(pf, vf, acc[dct]);
      }
    }
  }

  // epilogue: acc[dct][r] = O[q=g*4+r][d=dct*16+qh]; 1/lsum for row q' at lane q'
  const float inv = 1.0f / lsum;
  float invr[4];
  #pragma unroll
  for (int r = 0; r < 4; ++r) invr[r] = __shfl(inv, g * 4 + r, 64);
  #pragma unroll
  for (int dct = 0; dct < 4; ++dct) {
    const int col = h * DKH + dct * 16 + qh;
    #pragma unroll
    for (int r = 0; r < 4; ++r) {
      const int q = q0 + g * 4 + r;
      AO[(rb + q) * DMODEL + col] = (bf16_t)(acc[dct][r] * invr[r]);
    }
  }
}

extern "C" void kernel_launch(void* const* d_in, const int* in_sizes, int n_in,
                              void* d_out, int out_size, void* d_ws, size_t ws_size,
                              hipStream_t stream)
{
  const float* query = (const float*)d_in[0];
  const float* keyin = (const float*)d_in[1];
  const int*   mask  = (const int*)d_in[2];
  const float* Wq = (const float*)d_in[3];
  const float* bq = (const float*)d_in[4];
  const float* Wk = (const float*)d_in[5];
  const float* bk = (const float*)d_in[6];
  const float* Wv = (const float*)d_in[7];
  const float* bv = (const float*)d_in[8];
  const float* Wo = (const float*)d_in[9];
  const float* bo = (const float*)d_in[10];
  float* out = (float*)d_out;

  bf16_t* Qp = (bf16_t*)d_ws;
  bf16_t* Kp = Qp + (size_t)MROWS * DMODEL;
  bf16_t* Vp = Kp + (size_t)MROWS * DMODEL;
  bf16_t* AO = Vp + (size_t)MROWS * DMODEL;
  unsigned long long* Mpk = (unsigned long long*)(AO + (size_t)MROWS * DMODEL);

  dim3 blk(256);
  dim3 gproj(DMODEL / 64, MROWS / 64);

  mask_pack<<<dim3(4096), blk, 0, stream>>>(mask, Mpk);
  gemm_bias_act<256, true,  float,  bf16_t><<<gproj, blk, 0, stream>>>(query, Wq, bq, Qp, DMODEL, 1.0f);
  gemm_bias_act<256, true,  float,  bf16_t><<<gproj, blk, 0, stream>>>(keyin, Wk, bk, Kp, DMODEL, 0.125f);
  gemm_bias_act<256, true,  float,  bf16_t><<<gproj, blk, 0, stream>>>(keyin, Wv, bv, Vp, DMODEL, 1.0f);

  attn_kernel<<<dim3(NB * NH * (LQ / 64)), blk, 0, stream>>>(Qp, Kp, Vp, Mpk, AO);

  gemm_bias_act<512, false, bf16_t, float><<<gproj, blk, 0, stream>>>(AO, Wo, bo, out, DMODEL, 1.0f);
}

// Round 10
// 135.537 us; speedup vs baseline: 1.2569x; 1.0016x over previous
//
#include <hip/hip_runtime.h>
#include <hip/hip_bf16.h>
#include <type_traits>

typedef __bf16 bf16_t;
typedef __bf16 bf16x4 __attribute__((ext_vector_type(4)));
typedef __bf16 bf16x8 __attribute__((ext_vector_type(8)));
typedef float  f32x4  __attribute__((ext_vector_type(4)));

__device__ __forceinline__ f32x4 mfma16(bf16x8 a, bf16x8 b, f32x4 c) {
  return __builtin_amdgcn_mfma_f32_16x16x32_bf16(a, b, c, 0, 0, 0);
}

static constexpr int NB = 8;
static constexpr int LQ = 1024;
static constexpr int LKk = 1024;
static constexpr int DMODEL = 512;
static constexpr int NH = 8;
static constexpr int DKH = 64;
static constexpr int MROWS = NB * LQ;   // 8192
static constexpr int MWORDS = NB * LQ * (LKk / 64);  // 131072 u64 words

// swizzled byte offset for [R][128B] row-major LDS tiles (G4 XOR swizzle)
__device__ __forceinline__ int swz(int row, int byte) {
  return row * 128 + (byte ^ ((row & 7) << 4));
}

// ------- mask bit-pack v2: one u64 word per THREAD, 16 independent int4 loads
// (no __ballot -> no wave-serialized dependence; 16-deep MLP per thread).
__global__ __launch_bounds__(256)
void mask_pack(const int* __restrict__ mask, unsigned long long* __restrict__ mpk) {
  const int wd = blockIdx.x * 256 + threadIdx.x;
  const int4* base = reinterpret_cast<const int4*>(mask + (size_t)wd * 64);
  unsigned long long bits = 0;
  #pragma unroll
  for (int i = 0; i < 16; ++i) {
    int4 v = base[i];
    bits |= (unsigned long long)(v.x != 0) << (4 * i);
    bits |= (unsigned long long)(v.y != 0) << (4 * i + 1);
    bits |= (unsigned long long)(v.z != 0) << (4 * i + 2);
    bits |= (unsigned long long)(v.w != 0) << (4 * i + 3);
  }
  mpk[wd] = bits;
}

// C[M,N] = postscale * act(A[M,K] @ W[K,N] + bias)
template<int K, bool RELU, typename AT, typename OT>
__global__ __launch_bounds__(256)
void gemm_bias_act(const AT* __restrict__ A, const float* __restrict__ W,
                   const float* __restrict__ bias, OT* __restrict__ C, int N,
                   float postscale)
{
  __shared__ alignas(16) char Alds[64 * 128];
  __shared__ alignas(16) char Wlds[64 * 128];
  const int t = threadIdx.x;
  const int l = t & 63, w = t >> 6;
  const int m0 = blockIdx.y * 64, n0 = blockIdx.x * 64;

  f32x4 acc[4] = {};
  for (int k0 = 0; k0 < K; k0 += 64) {
    __syncthreads();
    {
      const int row = t >> 2, c0 = (t & 3) * 16;
      if constexpr (std::is_same<AT, float>::value) {
        const float4* ap = reinterpret_cast<const float4*>(A + (size_t)(m0 + row) * K + k0 + c0);
        #pragma unroll
        for (int j = 0; j < 4; ++j) {
          float4 f = ap[j];
          bf16x4 o = { (bf16_t)f.x, (bf16_t)f.y, (bf16_t)f.z, (bf16_t)f.w };
          *reinterpret_cast<bf16x4*>(&Alds[swz(row, (c0 + j * 4) * 2)]) = o;
        }
      } else {
        const bf16x8* ap = reinterpret_cast<const bf16x8*>(A + (size_t)(m0 + row) * K + k0 + c0);
        #pragma unroll
        for (int j = 0; j < 2; ++j)
          *reinterpret_cast<bf16x8*>(&Alds[swz(row, (c0 + j * 8) * 2)]) = ap[j];
      }
    }
    {
      const int k = t >> 2, nb = (t & 3) * 16;
      const float4* wp = reinterpret_cast<const float4*>(W + (size_t)(k0 + k) * N + n0 + nb);
      #pragma unroll
      for (int j = 0; j < 4; ++j) {
        float4 f = wp[j];
        float fv[4] = { f.x, f.y, f.z, f.w };
        #pragma unroll
        for (int i = 0; i < 4; ++i) {
          const int row = nb + j * 4 + i;
          *reinterpret_cast<bf16_t*>(&Wlds[swz(row, k * 2)]) = (bf16_t)fv[i];
        }
      }
    }
    __syncthreads();
    #pragma unroll
    for (int ks = 0; ks < 2; ++ks) {
      const int kb = (ks * 32 + ((l >> 4) * 8)) * 2;
      const int arow = w * 16 + (l & 15);
      bf16x8 af = *reinterpret_cast<const bf16x8*>(&Alds[swz(arow, kb)]);
      #pragma unroll
      for (int ct = 0; ct < 4; ++ct) {
        const int brow = ct * 16 + (l & 15);
        bf16x8 bfr = *reinterpret_cast<const bf16x8*>(&Wlds[swz(brow, kb)]);
        acc[ct] = mfma16(af, bfr, acc[ct]);
      }
    }
  }
  #pragma unroll
  for (int ct = 0; ct < 4; ++ct) {
    const int col = n0 + ct * 16 + (l & 15);
    const float bv = bias[col];
    #pragma unroll
    for (int r = 0; r < 4; ++r) {
      const int row = m0 + w * 16 + ((l >> 4) * 4) + r;
      float x = acc[ct][r] + bv;
      if constexpr (RELU) x = fmaxf(x, 0.f);
      C[(size_t)row * N + col] = (OT)(x * postscale);
    }
  }
}

// -- flash attention: swapped QK^T + lane-parallel softmax (R9-verified core)
//    + T14 async-STAGE split: next tile's K/V loaded to regs under compute.
__global__ __launch_bounds__(256)
void attn_kernel(const bf16_t* __restrict__ Qp, const bf16_t* __restrict__ Kp,
                 const bf16_t* __restrict__ Vp, const unsigned long long* __restrict__ Mpk,
                 bf16_t* __restrict__ AO)
{
  __shared__ alignas(16) char Klds[64 * 128];       // [kv][d] row-major, swizzled
  __shared__ alignas(16) char Vlds[64 * 128];       // [d][kv] transposed, swizzled
  __shared__ alignas(16) char Plds[4 * 16 * 128];   // per-wave [16 q][64 kv], swizzled
  const int t = threadIdx.x, l = t & 63, w = t >> 6;
  const int g = l >> 4, qh = l & 15;
  // XCD-aware swizzle (R8-proven): XCD x = bid%8 owns one batch.
  const int bid = (blockIdx.x & 7) * 128 + (blockIdx.x >> 3);
  const int qt = bid & 15, h = (bid >> 4) & 7, b = bid >> 7;
  const int q0 = qt * 64 + w * 16;   // this wave's 16 q rows
  const size_t rb = (size_t)b * LQ;

  // Q B-frag: lane (n=q=qh) provides B[k=d][q]; K pre-scaled by 1/8 in proj.
  bf16x8 qf[2];
  #pragma unroll
  for (int ks = 0; ks < 2; ++ks)
    qf[ks] = *reinterpret_cast<const bf16x8*>(
        Qp + (rb + q0 + qh) * DMODEL + h * DKH + ks * 32 + g * 8);

  const unsigned long long* mrow = Mpk + (rb + q0 + qh) * (LKk / 64);

  // staging-source bases (same element mapping as R9's staging)
  const int krow = t >> 2;                      // K: row t>>2, elems ((2t)&7)*8 ..
  const bf16_t* kbase = Kp + (rb + krow) * DMODEL + h * DKH + ((2 * t) & 7) * 8;
  const int vkv = t & 63, vd0 = (t >> 6) * 16;  // V: kv row, 16 d elems
  const bf16_t* vbase = Vp + (rb + vkv) * DMODEL + h * DKH + vd0;

  f32x4 acc[4] = {};                 // acc[dct][r] = O[q=g*4+r][d=dct*16+qh]
  float mrun = -1e30f, lsum = 0.f;   // softmax state for q = qh (x4 g-replicas)

  // T14 prologue: load tile 0 into regs
  bf16x8 kr0, kr1, vr0, vr1;
  kr0 = *reinterpret_cast<const bf16x8*>(kbase);
  kr1 = *reinterpret_cast<const bf16x8*>(kbase + 8);
  vr0 = *reinterpret_cast<const bf16x8*>(vbase);
  vr1 = *reinterpret_cast<const bf16x8*>(vbase + 8);

  for (int kv0 = 0; kv0 < LKk; kv0 += 64) {
    const unsigned long long mword = mrow[kv0 >> 6];

    __syncthreads();   // previous tile's compute done -> LDS writable
    // write staged regs -> LDS (byte image identical to R9)
    {
      const int cb = ((2 * t) & 7) * 16;
      *reinterpret_cast<bf16x8*>(&Klds[swz(krow, cb)]) = kr0;
      *reinterpret_cast<bf16x8*>(&Klds[swz(krow, cb + 16)]) = kr1;
      #pragma unroll
      for (int i = 0; i < 8; ++i)
        *reinterpret_cast<bf16_t*>(&Vlds[swz(vd0 + i, vkv * 2)]) = vr0[i];
      #pragma unroll
      for (int i = 0; i < 8; ++i)
        *reinterpret_cast<bf16_t*>(&Vlds[swz(vd0 + 8 + i, vkv * 2)]) = vr1[i];
    }
    __syncthreads();   // LDS ready

    // issue next tile's loads now; latency hides under compute below
    if (kv0 + 64 < LKk) {
      const bf16_t* kn = kbase + (size_t)(kv0 + 64) * DMODEL;
      const bf16_t* vn = vbase + (size_t)(kv0 + 64) * DMODEL;
      kr0 = *reinterpret_cast<const bf16x8*>(kn);
      kr1 = *reinterpret_cast<const bf16x8*>(kn + 8);
      vr0 = *reinterpret_cast<const bf16x8*>(vn);
      vr1 = *reinterpret_cast<const bf16x8*>(vn + 8);
    }

    // S^T = mfma(A=K, B=Q): D[m=kv][n=q]; lane holds kv = ct*16+g*4+r, q = qh
    f32x4 s[4] = {};
    #pragma unroll
    for (int ks = 0; ks < 2; ++ks) {
      const int kb = (ks * 32 + g * 8) * 2;
      #pragma unroll
      for (int ct = 0; ct < 4; ++ct) {
        bf16x8 kf = *reinterpret_cast<const bf16x8*>(&Klds[swz(ct * 16 + qh, kb)]);
        s[ct] = mfma16(kf, qf[ks], s[ct]);
      }
    }

    // mask + lane-parallel online softmax (single pass over 16 values)
    float p[4][4];
    float rmax = -1e30f;
    #pragma unroll
    for (int ct = 0; ct < 4; ++ct) {
      #pragma unroll
      for (int r = 0; r < 4; ++r) {
        float x = ((mword >> (ct * 16 + g * 4 + r)) & 1) ? s[ct][r] : -1e8f;
        p[ct][r] = x;
        rmax = fmaxf(rmax, x);
      }
    }
    rmax = fmaxf(rmax, __shfl_xor(rmax, 16));
    rmax = fmaxf(rmax, __shfl_xor(rmax, 32));
    const float newm = fmaxf(mrun, rmax);
    const float scale = __expf(mrun - newm);
    mrun = newm;

    float psum = 0.f;
    #pragma unroll
    for (int ct = 0; ct < 4; ++ct) {
      #pragma unroll
      for (int r = 0; r < 4; ++r) {
        p[ct][r] = __expf(p[ct][r] - newm);
        psum += p[ct][r];
      }
    }
    psum += __shfl_xor(psum, 16);
    psum += __shfl_xor(psum, 32);
    lsum = lsum * scale + psum;

    // unconditional O rescale (scale of q-row g*4+r lives at lane g*4+r)
    #pragma unroll
    for (int r = 0; r < 4; ++r) {
      const float sr = __shfl(scale, g * 4 + r, 64);
      #pragma unroll
      for (int dct = 0; dct < 4; ++dct) acc[dct][r] *= sr;
    }

    // write P[q=qh][kv=ct*16+g*4+r] — SCALAR bf16 stores only (curse rule)
    #pragma unroll
    for (int ct = 0; ct < 4; ++ct) {
      #pragma unroll
      for (int r = 0; r < 4; ++r)
        *reinterpret_cast<bf16_t*>(
            &Plds[w * 2048 + swz(qh, (ct * 16 + g * 4 + r) * 2)]) = (bf16_t)p[ct][r];
    }

    // O += P V   (A-frag rows q from Plds, B-frag from transposed Vlds)
    #pragma unroll
    for (int ks = 0; ks < 2; ++ks) {
      const int kb = (ks * 32 + g * 8) * 2;
      bf16x8 pf = *reinterpret_cast<const bf16x8*>(&Plds[w * 2048 + swz(qh, kb)]);
      #pragma unroll
      for (int dct = 0; dct < 4; ++dct) {
        bf16x8 vf = *reinterpret_cast<const bf16x8*>(&Vlds[swz(dct * 16 + qh, kb)]);
        acc[dct] = mfma16(pf, vf, acc[dct]);
      }
    }
  }

  // epilogue: acc[dct][r] = O[q=g*4+r][d=dct*16+qh]
  const float inv = 1.0f / lsum;
  float invr[4];
  #pragma unroll
  for (int r = 0; r < 4; ++r) invr[r] = __shfl(inv, g * 4 + r, 64);
  #pragma unroll
  for (int dct = 0; dct < 4; ++dct) {
    const int col = h * DKH + dct * 16 + qh;
    #pragma unroll
    for (int r = 0; r < 4; ++r) {
      const int q = q0 + g * 4 + r;
      AO[(rb + q) * DMODEL + col] = (bf16_t)(acc[dct][r] * invr[r]);
    }
  }
}

extern "C" void kernel_launch(void* const* d_in, const int* in_sizes, int n_in,
                              void* d_out, int out_size, void* d_ws, size_t ws_size,
                              hipStream_t stream)
{
  const float* query = (const float*)d_in[0];
  const float* keyin = (const float*)d_in[1];
  const int*   mask  = (const int*)d_in[2];
  const float* Wq = (const float*)d_in[3];
  const float* bq = (const float*)d_in[4];
  const float* Wk = (const float*)d_in[5];
  const float* bk = (const float*)d_in[6];
  const float* Wv = (const float*)d_in[7];
  const float* bv = (const float*)d_in[8];
  const float* Wo = (const float*)d_in[9];
  const float* bo = (const float*)d_in[10];
  float* out = (float*)d_out;

  bf16_t* Qp = (bf16_t*)d_ws;
  bf16_t* Kp = Qp + (size_t)MROWS * DMODEL;
  bf16_t* Vp = Kp + (size_t)MROWS * DMODEL;
  bf16_t* AO = Vp + (size_t)MROWS * DMODEL;
  unsigned long long* Mpk = (unsigned long long*)(AO + (size_t)MROWS * DMODEL);

  dim3 blk(256);
  dim3 gproj(DMODEL / 64, MROWS / 64);

  mask_pack<<<dim3(MWORDS / 256), blk, 0, stream>>>(mask, Mpk);
  gemm_bias_act<256, true,  float,  bf16_t><<<gproj, blk, 0, stream>>>(query, Wq, bq, Qp, DMODEL, 1.0f);
  gemm_bias_act<256, true,  float,  bf16_t><<<gproj, blk, 0, stream>>>(keyin, Wk, bk, Kp, DMODEL, 0.125f);
  gemm_bias_act<256, true,  float,  bf16_t><<<gproj, blk, 0, stream>>>(keyin, Wv, bv, Vp, DMODEL, 1.0f);

  attn_kernel<<<dim3(NB * NH * (LQ / 64)), blk, 0, stream>>>(Qp, Kp, Vp, Mpk, AO);

  gemm_bias_act<512, false, bf16_t, float><<<gproj, blk, 0, stream>>>(AO, Wo, bo, out, DMODEL, 1.0f);
}

// Round 11
// 127.220 us; speedup vs baseline: 1.3391x; 1.0654x over previous
//
#include <hip/hip_runtime.h>
#include <hip/hip_bf16.h>
#include <type_traits>

typedef __bf16 bf16_t;
typedef __bf16 bf16x4 __attribute__((ext_vector_type(4)));
typedef __bf16 bf16x8 __attribute__((ext_vector_type(8)));
typedef float  f32x4  __attribute__((ext_vector_type(4)));

__device__ __forceinline__ f32x4 mfma16(bf16x8 a, bf16x8 b, f32x4 c) {
  return __builtin_amdgcn_mfma_f32_16x16x32_bf16(a, b, c, 0, 0, 0);
}

static constexpr int NB = 8;
static constexpr int LQ = 1024;
static constexpr int LKk = 1024;
static constexpr int DMODEL = 512;
static constexpr int NH = 8;
static constexpr int DKH = 64;
static constexpr int MROWS = NB * LQ;   // 8192
static constexpr int MWORDS = NB * LQ * (LKk / 64);  // 131072 u64 words
// K prescale: 1/sqrt(64) folded with 1/ln(2) for exp2-domain softmax
#define KSCALE 0.1803368801111204f

// swizzled byte offset for [R][128B] row-major LDS tiles (G4 XOR swizzle)
__device__ __forceinline__ int swz(int row, int byte) {
  return row * 128 + (byte ^ ((row & 7) << 4));
}

// ------- mask bit-pack: one u64 word per THREAD, 16 independent int4 loads --
__global__ __launch_bounds__(256)
void mask_pack(const int* __restrict__ mask, unsigned long long* __restrict__ mpk) {
  const int wd = blockIdx.x * 256 + threadIdx.x;
  const int4* base = reinterpret_cast<const int4*>(mask + (size_t)wd * 64);
  unsigned long long bits = 0;
  #pragma unroll
  for (int i = 0; i < 16; ++i) {
    int4 v = base[i];
    bits |= (unsigned long long)(v.x != 0) << (4 * i);
    bits |= (unsigned long long)(v.y != 0) << (4 * i + 1);
    bits |= (unsigned long long)(v.z != 0) << (4 * i + 2);
    bits |= (unsigned long long)(v.w != 0) << (4 * i + 3);
  }
  mpk[wd] = bits;
}

// C[M,N] = postscale * act(A[M,K] @ W[K,N] + bias)
template<int K, bool RELU, typename AT, typename OT>
__global__ __launch_bounds__(256)
void gemm_bias_act(const AT* __restrict__ A, const float* __restrict__ W,
                   const float* __restrict__ bias, OT* __restrict__ C, int N,
                   float postscale)
{
  __shared__ alignas(16) char Alds[64 * 128];
  __shared__ alignas(16) char Wlds[64 * 128];
  const int t = threadIdx.x;
  const int l = t & 63, w = t >> 6;
  const int m0 = blockIdx.y * 64, n0 = blockIdx.x * 64;

  f32x4 acc[4] = {};
  for (int k0 = 0; k0 < K; k0 += 64) {
    __syncthreads();
    {
      const int row = t >> 2, c0 = (t & 3) * 16;
      if constexpr (std::is_same<AT, float>::value) {
        const float4* ap = reinterpret_cast<const float4*>(A + (size_t)(m0 + row) * K + k0 + c0);
        #pragma unroll
        for (int j = 0; j < 4; ++j) {
          float4 f = ap[j];
          bf16x4 o = { (bf16_t)f.x, (bf16_t)f.y, (bf16_t)f.z, (bf16_t)f.w };
          *reinterpret_cast<bf16x4*>(&Alds[swz(row, (c0 + j * 4) * 2)]) = o;
        }
      } else {
        const bf16x8* ap = reinterpret_cast<const bf16x8*>(A + (size_t)(m0 + row) * K + k0 + c0);
        #pragma unroll
        for (int j = 0; j < 2; ++j)
          *reinterpret_cast<bf16x8*>(&Alds[swz(row, (c0 + j * 8) * 2)]) = ap[j];
      }
    }
    {
      const int k = t >> 2, nb = (t & 3) * 16;
      const float4* wp = reinterpret_cast<const float4*>(W + (size_t)(k0 + k) * N + n0 + nb);
      #pragma unroll
      for (int j = 0; j < 4; ++j) {
        float4 f = wp[j];
        float fv[4] = { f.x, f.y, f.z, f.w };
        #pragma unroll
        for (int i = 0; i < 4; ++i) {
          const int row = nb + j * 4 + i;
          *reinterpret_cast<bf16_t*>(&Wlds[swz(row, k * 2)]) = (bf16_t)fv[i];
        }
      }
    }
    __syncthreads();
    #pragma unroll
    for (int ks = 0; ks < 2; ++ks) {
      const int kb = (ks * 32 + ((l >> 4) * 8)) * 2;
      const int arow = w * 16 + (l & 15);
      bf16x8 af = *reinterpret_cast<const bf16x8*>(&Alds[swz(arow, kb)]);
      #pragma unroll
      for (int ct = 0; ct < 4; ++ct) {
        const int brow = ct * 16 + (l & 15);
        bf16x8 bfr = *reinterpret_cast<const bf16x8*>(&Wlds[swz(brow, kb)]);
        acc[ct] = mfma16(af, bfr, acc[ct]);
      }
    }
  }
  #pragma unroll
  for (int ct = 0; ct < 4; ++ct) {
    const int col = n0 + ct * 16 + (l & 15);
    const float bv = bias[col];
    #pragma unroll
    for (int r = 0; r < 4; ++r) {
      const int row = m0 + w * 16 + ((l >> 4) * 4) + r;
      float x = acc[ct][r] + bv;
      if constexpr (RELU) x = fmaxf(x, 0.f);
      C[(size_t)row * N + col] = (OT)(x * postscale);
    }
  }
}

// -- flash attention: swapped QK^T, QBLK=32/wave (2 q-groups share K/V frags),
//    exp2-domain softmax, defer-rescale. R9-verified staging & P path.
__global__ __launch_bounds__(256)
void attn_kernel(const bf16_t* __restrict__ Qp, const bf16_t* __restrict__ Kp,
                 const bf16_t* __restrict__ Vp, const unsigned long long* __restrict__ Mpk,
                 bf16_t* __restrict__ AO)
{
  __shared__ alignas(16) char Klds[64 * 128];       // [kv][d] row-major, swizzled
  __shared__ alignas(16) char Vlds[64 * 128];       // [d][kv] transposed, swizzled
  __shared__ alignas(16) char Plds[4 * 32 * 128];   // per-wave [32 q][64 kv], swizzled
  const int t = threadIdx.x, l = t & 63, w = t >> 6;
  const int g = l >> 4, qh = l & 15;
  // XCD-aware swizzle: 512 blocks, XCD x = bid%8 owns batch x (64 blocks).
  const int bid = (blockIdx.x & 7) * 64 + (blockIdx.x >> 3);
  const int qt = bid & 7, h = (bid >> 3) & 7, b = bid >> 6;
  const int wq0 = qt * 128 + w * 32;   // this wave's 32 q rows (2 groups of 16)
  const size_t rb = (size_t)b * LQ;

  // Q B-frags: group j, lane provides B[k=d][q = wq0+j*16+qh]
  bf16x8 qf[2][2];
  #pragma unroll
  for (int j = 0; j < 2; ++j)
    #pragma unroll
    for (int ks = 0; ks < 2; ++ks)
      qf[j][ks] = *reinterpret_cast<const bf16x8*>(
          Qp + (rb + wq0 + j * 16 + qh) * DMODEL + h * DKH + ks * 32 + g * 8);

  const unsigned long long* mrow0 = Mpk + (rb + wq0 + qh) * (LKk / 64);
  const unsigned long long* mrow1 = Mpk + (rb + wq0 + 16 + qh) * (LKk / 64);

  f32x4 acc[2][4] = {};               // acc[j][dct][r] = O[wq0+j*16+g*4+r][dct*16+qh]
  float mrun[2] = { -1e30f, -1e30f }, lsum[2] = { 0.f, 0.f };

  for (int kv0 = 0; kv0 < LKk; kv0 += 64) {
    const unsigned long long mw[2] = { mrow0[kv0 >> 6], mrow1[kv0 >> 6] };

    __syncthreads();
    // stage K tile [64 kv][64 d] (2 x 16B per thread) — R9-proven
    {
      const int row = t >> 2, cb = ((2 * t) & 7) * 16;
      const bf16_t* src = Kp + (rb + kv0 + row) * DMODEL + h * DKH + cb / 2;
      *reinterpret_cast<bf16x8*>(&Klds[swz(row, cb)]) = *reinterpret_cast<const bf16x8*>(src);
      *reinterpret_cast<bf16x8*>(&Klds[swz(row, cb + 16)]) = *reinterpret_cast<const bf16x8*>(src + 8);
    }
    // stage V transposed: scalar bf16 stores, conflict-free remap (R8-proven)
    {
      const int kv = t & 63, d0 = (t >> 6) * 16;
      const bf16_t* s0 = Vp + (rb + kv0 + kv) * DMODEL + h * DKH + d0;
      bf16x8 v0 = *reinterpret_cast<const bf16x8*>(s0);
      bf16x8 v1 = *reinterpret_cast<const bf16x8*>(s0 + 8);
      #pragma unroll
      for (int i = 0; i < 8; ++i)
        *reinterpret_cast<bf16_t*>(&Vlds[swz(d0 + i, kv * 2)]) = v0[i];
      #pragma unroll
      for (int i = 0; i < 8; ++i)
        *reinterpret_cast<bf16_t*>(&Vlds[swz(d0 + 8 + i, kv * 2)]) = v1[i];
    }
    __syncthreads();

    // S^T = mfma(A=K, B=Q[j]): each K-frag read feeds both q-groups
    f32x4 s[2][4] = {};
    #pragma unroll
    for (int ks = 0; ks < 2; ++ks) {
      const int kb = (ks * 32 + g * 8) * 2;
      #pragma unroll
      for (int ct = 0; ct < 4; ++ct) {
        bf16x8 kf = *reinterpret_cast<const bf16x8*>(&Klds[swz(ct * 16 + qh, kb)]);
        s[0][ct] = mfma16(kf, qf[0][ks], s[0][ct]);
        s[1][ct] = mfma16(kf, qf[1][ks], s[1][ct]);
      }
    }

    // per-group mask + lane-parallel online softmax (exp2 domain)
    #pragma unroll
    for (int j = 0; j < 2; ++j) {
      float rmax = -1e30f;
      #pragma unroll
      for (int ct = 0; ct < 4; ++ct) {
        #pragma unroll
        for (int r = 0; r < 4; ++r) {
          float x = ((mw[j] >> (ct * 16 + g * 4 + r)) & 1) ? s[j][ct][r] : -1e8f;
          s[j][ct][r] = x;
          rmax = fmaxf(rmax, x);
        }
      }
      rmax = fmaxf(rmax, __shfl_xor(rmax, 16));
      rmax = fmaxf(rmax, __shfl_xor(rmax, 32));
      const float newm = fmaxf(mrun[j], rmax);

      if (__any(newm > mrun[j])) {   // defer-rescale: skip when max unchanged
        const float scale = __builtin_amdgcn_exp2f(mrun[j] - newm);
        lsum[j] *= scale;
        #pragma unroll
        for (int r = 0; r < 4; ++r) {
          const float sr = __shfl(scale, g * 4 + r, 64);
          #pragma unroll
          for (int dct = 0; dct < 4; ++dct) acc[j][dct][r] *= sr;
        }
        mrun[j] = newm;
      }

      float psum = 0.f;
      #pragma unroll
      for (int ct = 0; ct < 4; ++ct) {
        #pragma unroll
        for (int r = 0; r < 4; ++r) {
          const float pv = __builtin_amdgcn_exp2f(s[j][ct][r] - mrun[j]);
          s[j][ct][r] = pv;
          psum += pv;
        }
      }
      psum += __shfl_xor(psum, 16);
      psum += __shfl_xor(psum, 32);
      lsum[j] += psum;

      // P[q=j*16+qh][kv] — SCALAR bf16 stores only (curse rule)
      #pragma unroll
      for (int ct = 0; ct < 4; ++ct) {
        #pragma unroll
        for (int r = 0; r < 4; ++r)
          *reinterpret_cast<bf16_t*>(
              &Plds[w * 4096 + swz(j * 16 + qh, (ct * 16 + g * 4 + r) * 2)]) =
              (bf16_t)s[j][ct][r];
      }
    }

    // O += P V: each V-frag read feeds both q-groups
    #pragma unroll
    for (int ks = 0; ks < 2; ++ks) {
      const int kb = (ks * 32 + g * 8) * 2;
      bf16x8 pf0 = *reinterpret_cast<const bf16x8*>(&Plds[w * 4096 + swz(qh, kb)]);
      bf16x8 pf1 = *reinterpret_cast<const bf16x8*>(&Plds[w * 4096 + swz(16 + qh, kb)]);
      #pragma unroll
      for (int dct = 0; dct < 4; ++dct) {
        bf16x8 vf = *reinterpret_cast<const bf16x8*>(&Vlds[swz(dct * 16 + qh, kb)]);
        acc[0][dct] = mfma16(pf0, vf, acc[0][dct]);
        acc[1][dct] = mfma16(pf1, vf, acc[1][dct]);
      }
    }
  }

  // epilogue per group
  #pragma unroll
  for (int j = 0; j < 2; ++j) {
    const float inv = 1.0f / lsum[j];
    float invr[4];
    #pragma unroll
    for (int r = 0; r < 4; ++r) invr[r] = __shfl(inv, g * 4 + r, 64);
    #pragma unroll
    for (int dct = 0; dct < 4; ++dct) {
      const int col = h * DKH + dct * 16 + qh;
      #pragma unroll
      for (int r = 0; r < 4; ++r) {
        const int q = wq0 + j * 16 + g * 4 + r;
        AO[(rb + q) * DMODEL + col] = (bf16_t)(acc[j][dct][r] * invr[r]);
      }
    }
  }
}

extern "C" void kernel_launch(void* const* d_in, const int* in_sizes, int n_in,
                              void* d_out, int out_size, void* d_ws, size_t ws_size,
                              hipStream_t stream)
{
  const float* query = (const float*)d_in[0];
  const float* keyin = (const float*)d_in[1];
  const int*   mask  = (const int*)d_in[2];
  const float* Wq = (const float*)d_in[3];
  const float* bq = (const float*)d_in[4];
  const float* Wk = (const float*)d_in[5];
  const float* bk = (const float*)d_in[6];
  const float* Wv = (const float*)d_in[7];
  const float* bv = (const float*)d_in[8];
  const float* Wo = (const float*)d_in[9];
  const float* bo = (const float*)d_in[10];
  float* out = (float*)d_out;

  bf16_t* Qp = (bf16_t*)d_ws;
  bf16_t* Kp = Qp + (size_t)MROWS * DMODEL;
  bf16_t* Vp = Kp + (size_t)MROWS * DMODEL;
  bf16_t* AO = Vp + (size_t)MROWS * DMODEL;
  unsigned long long* Mpk = (unsigned long long*)(AO + (size_t)MROWS * DMODEL);

  dim3 blk(256);
  dim3 gproj(DMODEL / 64, MROWS / 64);

  mask_pack<<<dim3(MWORDS / 256), blk, 0, stream>>>(mask, Mpk);
  gemm_bias_act<256, true,  float,  bf16_t><<<gproj, blk, 0, stream>>>(query, Wq, bq, Qp, DMODEL, 1.0f);
  gemm_bias_act<256, true,  float,  bf16_t><<<gproj, blk, 0, stream>>>(keyin, Wk, bk, Kp, DMODEL, KSCALE);
  gemm_bias_act<256, true,  float,  bf16_t><<<gproj, blk, 0, stream>>>(keyin, Wv, bv, Vp, DMODEL, 1.0f);

  attn_kernel<<<dim3(NB * NH * (LQ / 128)), blk, 0, stream>>>(Qp, Kp, Vp, Mpk, AO);

  gemm_bias_act<512, false, bf16_t, float><<<gproj, blk, 0, stream>>>(AO, Wo, bo, out, DMODEL, 1.0f);
}

// Round 12
// 106.914 us; speedup vs baseline: 1.5934x; 1.1899x over previous
//
#include <hip/hip_runtime.h>
#include <hip/hip_bf16.h>
#include <type_traits>

typedef __bf16 bf16_t;
typedef __bf16 bf16x4 __attribute__((ext_vector_type(4)));
typedef __bf16 bf16x8 __attribute__((ext_vector_type(8)));
typedef float  f32x4  __attribute__((ext_vector_type(4)));

__device__ __forceinline__ f32x4 mfma16(bf16x8 a, bf16x8 b, f32x4 c) {
  return __builtin_amdgcn_mfma_f32_16x16x32_bf16(a, b, c, 0, 0, 0);
}

static constexpr int NB = 8;
static constexpr int LQ = 1024;
static constexpr int LKk = 1024;
static constexpr int DMODEL = 512;
static constexpr int NH = 8;
static constexpr int DKH = 64;
static constexpr int MROWS = NB * LQ;   // 8192
static constexpr int MWORDS = NB * LQ * (LKk / 64);  // 131072 u64 words
// K prescale: 1/sqrt(64) folded with 1/ln(2) for exp2-domain softmax
#define KSCALE 0.1803368801111204f

// swizzled byte offset for [R][128B] row-major LDS tiles (G4 XOR swizzle)
__device__ __forceinline__ int swz(int row, int byte) {
  return row * 128 + (byte ^ ((row & 7) << 4));
}

// ------- mask bit-pack: one u64 word per THREAD, 16 independent int4 loads --
__global__ __launch_bounds__(256)
void mask_pack(const int* __restrict__ mask, unsigned long long* __restrict__ mpk) {
  const int wd = blockIdx.x * 256 + threadIdx.x;
  const int4* base = reinterpret_cast<const int4*>(mask + (size_t)wd * 64);
  unsigned long long bits = 0;
  #pragma unroll
  for (int i = 0; i < 16; ++i) {
    int4 v = base[i];
    bits |= (unsigned long long)(v.x != 0) << (4 * i);
    bits |= (unsigned long long)(v.y != 0) << (4 * i + 1);
    bits |= (unsigned long long)(v.z != 0) << (4 * i + 2);
    bits |= (unsigned long long)(v.w != 0) << (4 * i + 3);
  }
  mpk[wd] = bits;
}

// ------- one-time weight transpose+convert: W f32 [K][N] -> Wt bf16 [N][K] --
// One 64x64 tile per block; LDS-staged transpose with scalar stores (curse-safe)
// and padded rows, then vector global writes.
__device__ __forceinline__ void wt_tile(const float* __restrict__ W, bf16_t* __restrict__ Wt,
                                        int K, int N, int kt, int nt, int t) {
  __shared__ bf16_t T[64][72];   // [n][k], +8 pad; row stride 144 B (16B-aligned)
  const int k0 = kt * 64, n0 = nt * 64;
  const int kr = t >> 2, c0 = (t & 3) * 16;
  const float4* src = reinterpret_cast<const float4*>(W + (size_t)(k0 + kr) * N + n0 + c0);
  #pragma unroll
  for (int j = 0; j < 4; ++j) {
    float4 f = src[j];
    T[c0 + j * 4 + 0][kr] = (bf16_t)f.x;
    T[c0 + j * 4 + 1][kr] = (bf16_t)f.y;
    T[c0 + j * 4 + 2][kr] = (bf16_t)f.z;
    T[c0 + j * 4 + 3][kr] = (bf16_t)f.w;
  }
  __syncthreads();
  const int nr = t >> 2, kc0 = (t & 3) * 16;
  bf16_t* dst = Wt + (size_t)(n0 + nr) * K + k0 + kc0;
  #pragma unroll
  for (int j = 0; j < 2; ++j)
    *reinterpret_cast<bf16x8*>(dst + j * 8) =
        *reinterpret_cast<const bf16x8*>(&T[nr][kc0 + j * 8]);
}

__global__ __launch_bounds__(256)
void weight_prep(const float* __restrict__ Wq, const float* __restrict__ Wk,
                 const float* __restrict__ Wv, const float* __restrict__ Wo,
                 bf16_t* __restrict__ Wtq, bf16_t* __restrict__ Wtk,
                 bf16_t* __restrict__ Wtv, bf16_t* __restrict__ Wto) {
  const int bidx = blockIdx.x, t = threadIdx.x;
  if (bidx < 32)        wt_tile(Wq, Wtq, 256, 512, bidx >> 3, bidx & 7, t);
  else if (bidx < 64)   wt_tile(Wk, Wtk, 256, 512, (bidx - 32) >> 3, bidx & 7, t);
  else if (bidx < 96)   wt_tile(Wv, Wtv, 256, 512, (bidx - 64) >> 3, bidx & 7, t);
  else                  wt_tile(Wo, Wto, 512, 512, (bidx - 96) >> 3, bidx & 7, t);
}

// C[M,512] = postscale * act(A[M,K] @ Wt[512,K]^T + bias); Wt pre-transposed bf16.
// Grid 1024 blocks, XCD-chunked: each XCD owns 16 m-tiles x 8 n-tiles.
template<int K, bool RELU, typename AT, typename OT>
__global__ __launch_bounds__(256)
void gemm_bias_act(const AT* __restrict__ A, const bf16_t* __restrict__ Wt,
                   const float* __restrict__ bias, OT* __restrict__ C,
                   float postscale)
{
  constexpr int N = 512;
  __shared__ alignas(16) char Alds[64 * 128];
  __shared__ alignas(16) char Wlds[64 * 128];
  const int t = threadIdx.x;
  const int l = t & 63, w = t >> 6;
  const int xcd = blockIdx.x & 7, idx = blockIdx.x >> 3;
  const int m0 = (xcd * 16 + (idx >> 3)) * 64, n0 = (idx & 7) * 64;

  f32x4 acc[4] = {};
  for (int k0 = 0; k0 < K; k0 += 64) {
    __syncthreads();
    // stage A [64 m][64 k]
    if constexpr (std::is_same<AT, float>::value) {
      const int row = t >> 2, c0 = (t & 3) * 16;
      const float4* ap = reinterpret_cast<const float4*>(A + (size_t)(m0 + row) * K + k0 + c0);
      #pragma unroll
      for (int j = 0; j < 4; ++j) {
        float4 f = ap[j];
        bf16x4 o = { (bf16_t)f.x, (bf16_t)f.y, (bf16_t)f.z, (bf16_t)f.w };
        *reinterpret_cast<bf16x4*>(&Alds[swz(row, (c0 + j * 4) * 2)]) = o;
      }
    } else {
      const int row = t >> 2, cb = ((2 * t) & 7) * 16;
      const bf16_t* src = A + (size_t)(m0 + row) * K + k0 + cb / 2;
      *reinterpret_cast<bf16x8*>(&Alds[swz(row, cb)]) = *reinterpret_cast<const bf16x8*>(src);
      *reinterpret_cast<bf16x8*>(&Alds[swz(row, cb + 16)]) = *reinterpret_cast<const bf16x8*>(src + 8);
    }
    // stage Wt [64 n][64 k] — vector 16B loads/stores (attn-K-staging pattern)
    {
      const int row = t >> 2, cb = ((2 * t) & 7) * 16;
      const bf16_t* src = Wt + (size_t)(n0 + row) * K + k0 + cb / 2;
      *reinterpret_cast<bf16x8*>(&Wlds[swz(row, cb)]) = *reinterpret_cast<const bf16x8*>(src);
      *reinterpret_cast<bf16x8*>(&Wlds[swz(row, cb + 16)]) = *reinterpret_cast<const bf16x8*>(src + 8);
    }
    __syncthreads();
    #pragma unroll
    for (int ks = 0; ks < 2; ++ks) {
      const int kb = (ks * 32 + ((l >> 4) * 8)) * 2;
      const int arow = w * 16 + (l & 15);
      bf16x8 af = *reinterpret_cast<const bf16x8*>(&Alds[swz(arow, kb)]);
      #pragma unroll
      for (int ct = 0; ct < 4; ++ct) {
        const int brow = ct * 16 + (l & 15);
        bf16x8 bfr = *reinterpret_cast<const bf16x8*>(&Wlds[swz(brow, kb)]);
        acc[ct] = mfma16(af, bfr, acc[ct]);
      }
    }
  }
  #pragma unroll
  for (int ct = 0; ct < 4; ++ct) {
    const int col = n0 + ct * 16 + (l & 15);
    const float bv = bias[col];
    #pragma unroll
    for (int r = 0; r < 4; ++r) {
      const int row = m0 + w * 16 + ((l >> 4) * 4) + r;
      float x = acc[ct][r] + bv;
      if constexpr (RELU) x = fmaxf(x, 0.f);
      C[(size_t)row * N + col] = (OT)(x * postscale);
    }
  }
}

// -- flash attention: R11-verified (swapped QK^T, QBLK=32, exp2, defer-rescale)
__global__ __launch_bounds__(256)
void attn_kernel(const bf16_t* __restrict__ Qp, const bf16_t* __restrict__ Kp,
                 const bf16_t* __restrict__ Vp, const unsigned long long* __restrict__ Mpk,
                 bf16_t* __restrict__ AO)
{
  __shared__ alignas(16) char Klds[64 * 128];       // [kv][d] row-major, swizzled
  __shared__ alignas(16) char Vlds[64 * 128];       // [d][kv] transposed, swizzled
  __shared__ alignas(16) char Plds[4 * 32 * 128];   // per-wave [32 q][64 kv], swizzled
  const int t = threadIdx.x, l = t & 63, w = t >> 6;
  const int g = l >> 4, qh = l & 15;
  const int bid = (blockIdx.x & 7) * 64 + (blockIdx.x >> 3);
  const int qt = bid & 7, h = (bid >> 3) & 7, b = bid >> 6;
  const int wq0 = qt * 128 + w * 32;
  const size_t rb = (size_t)b * LQ;

  bf16x8 qf[2][2];
  #pragma unroll
  for (int j = 0; j < 2; ++j)
    #pragma unroll
    for (int ks = 0; ks < 2; ++ks)
      qf[j][ks] = *reinterpret_cast<const bf16x8*>(
          Qp + (rb + wq0 + j * 16 + qh) * DMODEL + h * DKH + ks * 32 + g * 8);

  const unsigned long long* mrow0 = Mpk + (rb + wq0 + qh) * (LKk / 64);
  const unsigned long long* mrow1 = Mpk + (rb + wq0 + 16 + qh) * (LKk / 64);

  f32x4 acc[2][4] = {};
  float mrun[2] = { -1e30f, -1e30f }, lsum[2] = { 0.f, 0.f };

  for (int kv0 = 0; kv0 < LKk; kv0 += 64) {
    const unsigned long long mw[2] = { mrow0[kv0 >> 6], mrow1[kv0 >> 6] };

    __syncthreads();
    {
      const int row = t >> 2, cb = ((2 * t) & 7) * 16;
      const bf16_t* src = Kp + (rb + kv0 + row) * DMODEL + h * DKH + cb / 2;
      *reinterpret_cast<bf16x8*>(&Klds[swz(row, cb)]) = *reinterpret_cast<const bf16x8*>(src);
      *reinterpret_cast<bf16x8*>(&Klds[swz(row, cb + 16)]) = *reinterpret_cast<const bf16x8*>(src + 8);
    }
    {
      const int kv = t & 63, d0 = (t >> 6) * 16;
      const bf16_t* s0 = Vp + (rb + kv0 + kv) * DMODEL + h * DKH + d0;
      bf16x8 v0 = *reinterpret_cast<const bf16x8*>(s0);
      bf16x8 v1 = *reinterpret_cast<const bf16x8*>(s0 + 8);
      #pragma unroll
      for (int i = 0; i < 8; ++i)
        *reinterpret_cast<bf16_t*>(&Vlds[swz(d0 + i, kv * 2)]) = v0[i];
      #pragma unroll
      for (int i = 0; i < 8; ++i)
        *reinterpret_cast<bf16_t*>(&Vlds[swz(d0 + 8 + i, kv * 2)]) = v1[i];
    }
    __syncthreads();

    f32x4 s[2][4] = {};
    #pragma unroll
    for (int ks = 0; ks < 2; ++ks) {
      const int kb = (ks * 32 + g * 8) * 2;
      #pragma unroll
      for (int ct = 0; ct < 4; ++ct) {
        bf16x8 kf = *reinterpret_cast<const bf16x8*>(&Klds[swz(ct * 16 + qh, kb)]);
        s[0][ct] = mfma16(kf, qf[0][ks], s[0][ct]);
        s[1][ct] = mfma16(kf, qf[1][ks], s[1][ct]);
      }
    }

    #pragma unroll
    for (int j = 0; j < 2; ++j) {
      float rmax = -1e30f;
      #pragma unroll
      for (int ct = 0; ct < 4; ++ct) {
        #pragma unroll
        for (int r = 0; r < 4; ++r) {
          float x = ((mw[j] >> (ct * 16 + g * 4 + r)) & 1) ? s[j][ct][r] : -1e8f;
          s[j][ct][r] = x;
          rmax = fmaxf(rmax, x);
        }
      }
      rmax = fmaxf(rmax, __shfl_xor(rmax, 16));
      rmax = fmaxf(rmax, __shfl_xor(rmax, 32));
      const float newm = fmaxf(mrun[j], rmax);

      if (__any(newm > mrun[j])) {
        const float scale = __builtin_amdgcn_exp2f(mrun[j] - newm);
        lsum[j] *= scale;
        #pragma unroll
        for (int r = 0; r < 4; ++r) {
          const float sr = __shfl(scale, g * 4 + r, 64);
          #pragma unroll
          for (int dct = 0; dct < 4; ++dct) acc[j][dct][r] *= sr;
        }
        mrun[j] = newm;
      }

      float psum = 0.f;
      #pragma unroll
      for (int ct = 0; ct < 4; ++ct) {
        #pragma unroll
        for (int r = 0; r < 4; ++r) {
          const float pv = __builtin_amdgcn_exp2f(s[j][ct][r] - mrun[j]);
          s[j][ct][r] = pv;
          psum += pv;
        }
      }
      psum += __shfl_xor(psum, 16);
      psum += __shfl_xor(psum, 32);
      lsum[j] += psum;

      #pragma unroll
      for (int ct = 0; ct < 4; ++ct) {
        #pragma unroll
        for (int r = 0; r < 4; ++r)
          *reinterpret_cast<bf16_t*>(
              &Plds[w * 4096 + swz(j * 16 + qh, (ct * 16 + g * 4 + r) * 2)]) =
              (bf16_t)s[j][ct][r];
      }
    }

    #pragma unroll
    for (int ks = 0; ks < 2; ++ks) {
      const int kb = (ks * 32 + g * 8) * 2;
      bf16x8 pf0 = *reinterpret_cast<const bf16x8*>(&Plds[w * 4096 + swz(qh, kb)]);
      bf16x8 pf1 = *reinterpret_cast<const bf16x8*>(&Plds[w * 4096 + swz(16 + qh, kb)]);
      #pragma unroll
      for (int dct = 0; dct < 4; ++dct) {
        bf16x8 vf = *reinterpret_cast<const bf16x8*>(&Vlds[swz(dct * 16 + qh, kb)]);
        acc[0][dct] = mfma16(pf0, vf, acc[0][dct]);
        acc[1][dct] = mfma16(pf1, vf, acc[1][dct]);
      }
    }
  }

  #pragma unroll
  for (int j = 0; j < 2; ++j) {
    const float inv = 1.0f / lsum[j];
    float invr[4];
    #pragma unroll
    for (int r = 0; r < 4; ++r) invr[r] = __shfl(inv, g * 4 + r, 64);
    #pragma unroll
    for (int dct = 0; dct < 4; ++dct) {
      const int col = h * DKH + dct * 16 + qh;
      #pragma unroll
      for (int r = 0; r < 4; ++r) {
        const int q = wq0 + j * 16 + g * 4 + r;
        AO[(rb + q) * DMODEL + col] = (bf16_t)(acc[j][dct][r] * invr[r]);
      }
    }
  }
}

extern "C" void kernel_launch(void* const* d_in, const int* in_sizes, int n_in,
                              void* d_out, int out_size, void* d_ws, size_t ws_size,
                              hipStream_t stream)
{
  const float* query = (const float*)d_in[0];
  const float* keyin = (const float*)d_in[1];
  const int*   mask  = (const int*)d_in[2];
  const float* Wq = (const float*)d_in[3];
  const float* bq = (const float*)d_in[4];
  const float* Wk = (const float*)d_in[5];
  const float* bk = (const float*)d_in[6];
  const float* Wv = (const float*)d_in[7];
  const float* bv = (const float*)d_in[8];
  const float* Wo = (const float*)d_in[9];
  const float* bo = (const float*)d_in[10];
  float* out = (float*)d_out;

  bf16_t* Qp = (bf16_t*)d_ws;
  bf16_t* Kp = Qp + (size_t)MROWS * DMODEL;
  bf16_t* Vp = Kp + (size_t)MROWS * DMODEL;
  bf16_t* AO = Vp + (size_t)MROWS * DMODEL;
  unsigned long long* Mpk = (unsigned long long*)(AO + (size_t)MROWS * DMODEL);
  bf16_t* Wtq = (bf16_t*)(Mpk + MWORDS);          // 512x256
  bf16_t* Wtk = Wtq + 512 * 256;                  // 512x256
  bf16_t* Wtv = Wtk + 512 * 256;                  // 512x256
  bf16_t* Wto = Wtv + 512 * 256;                  // 512x512
  // ws total ~34.25 MB

  dim3 blk(256);

  weight_prep<<<dim3(160), blk, 0, stream>>>(Wq, Wk, Wv, Wo, Wtq, Wtk, Wtv, Wto);
  mask_pack<<<dim3(MWORDS / 256), blk, 0, stream>>>(mask, Mpk);
  gemm_bias_act<256, true,  float,  bf16_t><<<dim3(1024), blk, 0, stream>>>(query, Wtq, bq, Qp, 1.0f);
  gemm_bias_act<256, true,  float,  bf16_t><<<dim3(1024), blk, 0, stream>>>(keyin, Wtk, bk, Kp, KSCALE);
  gemm_bias_act<256, true,  float,  bf16_t><<<dim3(1024), blk, 0, stream>>>(keyin, Wtv, bv, Vp, 1.0f);

  attn_kernel<<<dim3(NB * NH * (LQ / 128)), blk, 0, stream>>>(Qp, Kp, Vp, Mpk, AO);

  gemm_bias_act<512, false, bf16_t, float><<<dim3(1024), blk, 0, stream>>>(AO, Wto, bo, out, 1.0f);
}

// Round 13
// 106.144 us; speedup vs baseline: 1.6050x; 1.0072x over previous
//
#include <hip/hip_runtime.h>
#include <hip/hip_bf16.h>
#include <type_traits>

typedef __bf16 bf16_t;
typedef __bf16 bf16x4 __attribute__((ext_vector_type(4)));
typedef __bf16 bf16x8 __attribute__((ext_vector_type(8)));
typedef float  f32x4  __attribute__((ext_vector_type(4)));

__device__ __forceinline__ f32x4 mfma16(bf16x8 a, bf16x8 b, f32x4 c) {
  return __builtin_amdgcn_mfma_f32_16x16x32_bf16(a, b, c, 0, 0, 0);
}

static constexpr int NB = 8;
static constexpr int LQ = 1024;
static constexpr int LKk = 1024;
static constexpr int DMODEL = 512;
static constexpr int NH = 8;
static constexpr int DKH = 64;
static constexpr int MROWS = NB * LQ;   // 8192
static constexpr int MWORDS = NB * LQ * (LKk / 64);  // 131072 u64 words
// K prescale: 1/sqrt(64) folded with 1/ln(2) for exp2-domain softmax
#define KSCALE 0.1803368801111204f

// swizzled byte offset for [R][128B] row-major LDS tiles (G4 XOR swizzle)
__device__ __forceinline__ int swz(int row, int byte) {
  return row * 128 + (byte ^ ((row & 7) << 4));
}

// ------- mask bit-pack: one u64 word per THREAD, 16 independent int4 loads --
__global__ __launch_bounds__(256)
void mask_pack(const int* __restrict__ mask, unsigned long long* __restrict__ mpk) {
  const int wd = blockIdx.x * 256 + threadIdx.x;
  const int4* base = reinterpret_cast<const int4*>(mask + (size_t)wd * 64);
  unsigned long long bits = 0;
  #pragma unroll
  for (int i = 0; i < 16; ++i) {
    int4 v = base[i];
    bits |= (unsigned long long)(v.x != 0) << (4 * i);
    bits |= (unsigned long long)(v.y != 0) << (4 * i + 1);
    bits |= (unsigned long long)(v.z != 0) << (4 * i + 2);
    bits |= (unsigned long long)(v.w != 0) << (4 * i + 3);
  }
  mpk[wd] = bits;
}

// ------- one-time weight transpose+convert: W f32 [K][N] -> Wt bf16 [N][K] --
__device__ __forceinline__ void wt_tile(const float* __restrict__ W, bf16_t* __restrict__ Wt,
                                        int K, int N, int kt, int nt, int t) {
  __shared__ bf16_t T[64][72];
  const int k0 = kt * 64, n0 = nt * 64;
  const int kr = t >> 2, c0 = (t & 3) * 16;
  const float4* src = reinterpret_cast<const float4*>(W + (size_t)(k0 + kr) * N + n0 + c0);
  #pragma unroll
  for (int j = 0; j < 4; ++j) {
    float4 f = src[j];
    T[c0 + j * 4 + 0][kr] = (bf16_t)f.x;
    T[c0 + j * 4 + 1][kr] = (bf16_t)f.y;
    T[c0 + j * 4 + 2][kr] = (bf16_t)f.z;
    T[c0 + j * 4 + 3][kr] = (bf16_t)f.w;
  }
  __syncthreads();
  const int nr = t >> 2, kc0 = (t & 3) * 16;
  bf16_t* dst = Wt + (size_t)(n0 + nr) * K + k0 + kc0;
  #pragma unroll
  for (int j = 0; j < 2; ++j)
    *reinterpret_cast<bf16x8*>(dst + j * 8) =
        *reinterpret_cast<const bf16x8*>(&T[nr][kc0 + j * 8]);
}

__global__ __launch_bounds__(256)
void weight_prep(const float* __restrict__ Wq, const float* __restrict__ Wk,
                 const float* __restrict__ Wv, const float* __restrict__ Wo,
                 bf16_t* __restrict__ Wtq, bf16_t* __restrict__ Wtk,
                 bf16_t* __restrict__ Wtv, bf16_t* __restrict__ Wto) {
  const int bidx = blockIdx.x, t = threadIdx.x;
  if (bidx < 32)        wt_tile(Wq, Wtq, 256, 512, bidx >> 3, bidx & 7, t);
  else if (bidx < 64)   wt_tile(Wk, Wtk, 256, 512, (bidx - 32) >> 3, bidx & 7, t);
  else if (bidx < 96)   wt_tile(Wv, Wtv, 256, 512, (bidx - 64) >> 3, bidx & 7, t);
  else                  wt_tile(Wo, Wto, 512, 512, (bidx - 96) >> 3, bidx & 7, t);
}

// C[M,512] = postscale * act(A @ Wt^T + bias); single-output version (Q, out-proj)
template<int K, bool RELU, typename AT, typename OT>
__global__ __launch_bounds__(256)
void gemm_bias_act(const AT* __restrict__ A, const bf16_t* __restrict__ Wt,
                   const float* __restrict__ bias, OT* __restrict__ C,
                   float postscale)
{
  constexpr int N = 512;
  __shared__ alignas(16) char Alds[64 * 128];
  __shared__ alignas(16) char Wlds[64 * 128];
  const int t = threadIdx.x;
  const int l = t & 63, w = t >> 6;
  const int xcd = blockIdx.x & 7, idx = blockIdx.x >> 3;
  const int m0 = (xcd * 16 + (idx >> 3)) * 64, n0 = (idx & 7) * 64;

  f32x4 acc[4] = {};
  for (int k0 = 0; k0 < K; k0 += 64) {
    __syncthreads();
    if constexpr (std::is_same<AT, float>::value) {
      const int row = t >> 2, c0 = (t & 3) * 16;
      const float4* ap = reinterpret_cast<const float4*>(A + (size_t)(m0 + row) * K + k0 + c0);
      #pragma unroll
      for (int j = 0; j < 4; ++j) {
        float4 f = ap[j];
        bf16x4 o = { (bf16_t)f.x, (bf16_t)f.y, (bf16_t)f.z, (bf16_t)f.w };
        *reinterpret_cast<bf16x4*>(&Alds[swz(row, (c0 + j * 4) * 2)]) = o;
      }
    } else {
      const int row = t >> 2, cb = ((2 * t) & 7) * 16;
      const bf16_t* src = A + (size_t)(m0 + row) * K + k0 + cb / 2;
      *reinterpret_cast<bf16x8*>(&Alds[swz(row, cb)]) = *reinterpret_cast<const bf16x8*>(src);
      *reinterpret_cast<bf16x8*>(&Alds[swz(row, cb + 16)]) = *reinterpret_cast<const bf16x8*>(src + 8);
    }
    {
      const int row = t >> 2, cb = ((2 * t) & 7) * 16;
      const bf16_t* src = Wt + (size_t)(n0 + row) * K + k0 + cb / 2;
      *reinterpret_cast<bf16x8*>(&Wlds[swz(row, cb)]) = *reinterpret_cast<const bf16x8*>(src);
      *reinterpret_cast<bf16x8*>(&Wlds[swz(row, cb + 16)]) = *reinterpret_cast<const bf16x8*>(src + 8);
    }
    __syncthreads();
    #pragma unroll
    for (int ks = 0; ks < 2; ++ks) {
      const int kb = (ks * 32 + ((l >> 4) * 8)) * 2;
      const int arow = w * 16 + (l & 15);
      bf16x8 af = *reinterpret_cast<const bf16x8*>(&Alds[swz(arow, kb)]);
      #pragma unroll
      for (int ct = 0; ct < 4; ++ct) {
        const int brow = ct * 16 + (l & 15);
        bf16x8 bfr = *reinterpret_cast<const bf16x8*>(&Wlds[swz(brow, kb)]);
        acc[ct] = mfma16(af, bfr, acc[ct]);
      }
    }
  }
  #pragma unroll
  for (int ct = 0; ct < 4; ++ct) {
    const int col = n0 + ct * 16 + (l & 15);
    const float bv = bias[col];
    #pragma unroll
    for (int r = 0; r < 4; ++r) {
      const int row = m0 + w * 16 + ((l >> 4) * 4) + r;
      float x = acc[ct][r] + bv;
      if constexpr (RELU) x = fmaxf(x, 0.f);
      C[(size_t)row * N + col] = (OT)(x * postscale);
    }
  }
}

// ------- merged K+V projection: shared A staging, two W streams -------------
__global__ __launch_bounds__(256)
void gemm_kv(const float* __restrict__ A, const bf16_t* __restrict__ Wtk,
             const bf16_t* __restrict__ Wtv, const float* __restrict__ bk,
             const float* __restrict__ bv, bf16_t* __restrict__ Ck,
             bf16_t* __restrict__ Cv)
{
  constexpr int K = 256, N = 512;
  __shared__ alignas(16) char Alds[64 * 128];
  __shared__ alignas(16) char Wk_lds[64 * 128];
  __shared__ alignas(16) char Wv_lds[64 * 128];
  const int t = threadIdx.x;
  const int l = t & 63, w = t >> 6;
  const int xcd = blockIdx.x & 7, idx = blockIdx.x >> 3;
  const int m0 = (xcd * 16 + (idx >> 3)) * 64, n0 = (idx & 7) * 64;

  f32x4 acck[4] = {}, accv[4] = {};
  for (int k0 = 0; k0 < K; k0 += 64) {
    __syncthreads();
    {
      const int row = t >> 2, c0 = (t & 3) * 16;
      const float4* ap = reinterpret_cast<const float4*>(A + (size_t)(m0 + row) * K + k0 + c0);
      #pragma unroll
      for (int j = 0; j < 4; ++j) {
        float4 f = ap[j];
        bf16x4 o = { (bf16_t)f.x, (bf16_t)f.y, (bf16_t)f.z, (bf16_t)f.w };
        *reinterpret_cast<bf16x4*>(&Alds[swz(row, (c0 + j * 4) * 2)]) = o;
      }
    }
    {
      const int row = t >> 2, cb = ((2 * t) & 7) * 16;
      const bf16_t* sk = Wtk + (size_t)(n0 + row) * K + k0 + cb / 2;
      const bf16_t* sv = Wtv + (size_t)(n0 + row) * K + k0 + cb / 2;
      *reinterpret_cast<bf16x8*>(&Wk_lds[swz(row, cb)]) = *reinterpret_cast<const bf16x8*>(sk);
      *reinterpret_cast<bf16x8*>(&Wk_lds[swz(row, cb + 16)]) = *reinterpret_cast<const bf16x8*>(sk + 8);
      *reinterpret_cast<bf16x8*>(&Wv_lds[swz(row, cb)]) = *reinterpret_cast<const bf16x8*>(sv);
      *reinterpret_cast<bf16x8*>(&Wv_lds[swz(row, cb + 16)]) = *reinterpret_cast<const bf16x8*>(sv + 8);
    }
    __syncthreads();
    #pragma unroll
    for (int ks = 0; ks < 2; ++ks) {
      const int kb = (ks * 32 + ((l >> 4) * 8)) * 2;
      const int arow = w * 16 + (l & 15);
      bf16x8 af = *reinterpret_cast<const bf16x8*>(&Alds[swz(arow, kb)]);
      #pragma unroll
      for (int ct = 0; ct < 4; ++ct) {
        const int brow = ct * 16 + (l & 15);
        bf16x8 bk8 = *reinterpret_cast<const bf16x8*>(&Wk_lds[swz(brow, kb)]);
        bf16x8 bv8 = *reinterpret_cast<const bf16x8*>(&Wv_lds[swz(brow, kb)]);
        acck[ct] = mfma16(af, bk8, acck[ct]);
        accv[ct] = mfma16(af, bv8, accv[ct]);
      }
    }
  }
  #pragma unroll
  for (int ct = 0; ct < 4; ++ct) {
    const int col = n0 + ct * 16 + (l & 15);
    const float bkv = bk[col], bvv = bv[col];
    #pragma unroll
    for (int r = 0; r < 4; ++r) {
      const int row = m0 + w * 16 + ((l >> 4) * 4) + r;
      Ck[(size_t)row * N + col] = (bf16_t)(fmaxf(acck[ct][r] + bkv, 0.f) * KSCALE);
      Cv[(size_t)row * N + col] = (bf16_t)fmaxf(accv[ct][r] + bvv, 0.f);
    }
  }
}

// -- flash attention: R11-verified per-wave core; 8-wave blocks with
//    intra-block KV-split (waves 0-3: kv 0-511, waves 4-7: kv 512-1023),
//    LDS flash-combine at the end. 16 waves/CU resident (was 8).
__global__ __launch_bounds__(512)
void attn_kernel(const bf16_t* __restrict__ Qp, const bf16_t* __restrict__ Kp,
                 const bf16_t* __restrict__ Vp, const unsigned long long* __restrict__ Mpk,
                 bf16_t* __restrict__ AO)
{
  __shared__ alignas(16) char SMEM[65536];
  const int t = threadIdx.x, l = t & 63;
  const int wave = t >> 6;           // 0..7
  const int hw = wave >> 2;          // kv-half
  const int w4 = wave & 3;           // wave within half
  const int th = t & 255;            // thread within half
  const int g = l >> 4, qh = l & 15;
  const int bid = (blockIdx.x & 7) * 64 + (blockIdx.x >> 3);
  const int qt = bid & 7, h = (bid >> 3) & 7, b = bid >> 6;
  const int wq0 = qt * 128 + w4 * 32;
  const size_t rb = (size_t)b * LQ;

  char* Klds = SMEM + hw * 8192;             // per-half [64 kv][128 B]
  char* Vlds = SMEM + 16384 + hw * 8192;     // per-half [64 d][128 B] transposed
  char* Pw   = SMEM + 32768 + wave * 4096;   // per-wave [32 q][128 B]

  bf16x8 qf[2][2];
  #pragma unroll
  for (int j = 0; j < 2; ++j)
    #pragma unroll
    for (int ks = 0; ks < 2; ++ks)
      qf[j][ks] = *reinterpret_cast<const bf16x8*>(
          Qp + (rb + wq0 + j * 16 + qh) * DMODEL + h * DKH + ks * 32 + g * 8);

  const unsigned long long* mrow0 = Mpk + (rb + wq0 + qh) * (LKk / 64);
  const unsigned long long* mrow1 = Mpk + (rb + wq0 + 16 + qh) * (LKk / 64);

  f32x4 acc[2][4] = {};
  float mrun[2] = { -1e30f, -1e30f }, lsum[2] = { 0.f, 0.f };

  const int kvbase = hw * 512;
  for (int kt = 0; kt < 8; ++kt) {
    const int kv0 = kvbase + kt * 64;
    const unsigned long long mw[2] = { mrow0[kv0 >> 6], mrow1[kv0 >> 6] };

    __syncthreads();
    // stage K tile (per half; thread mapping = R9-proven with th)
    {
      const int row = th >> 2, cb = ((2 * th) & 7) * 16;
      const bf16_t* src = Kp + (rb + kv0 + row) * DMODEL + h * DKH + cb / 2;
      *reinterpret_cast<bf16x8*>(&Klds[swz(row, cb)]) = *reinterpret_cast<const bf16x8*>(src);
      *reinterpret_cast<bf16x8*>(&Klds[swz(row, cb + 16)]) = *reinterpret_cast<const bf16x8*>(src + 8);
    }
    // stage V transposed (scalar bf16 stores, R8-proven mapping with th)
    {
      const int kv = th & 63, d0 = (th >> 6) * 16;
      const bf16_t* s0 = Vp + (rb + kv0 + kv) * DMODEL + h * DKH + d0;
      bf16x8 v0 = *reinterpret_cast<const bf16x8*>(s0);
      bf16x8 v1 = *reinterpret_cast<const bf16x8*>(s0 + 8);
      #pragma unroll
      for (int i = 0; i < 8; ++i)
        *reinterpret_cast<bf16_t*>(&Vlds[swz(d0 + i, kv * 2)]) = v0[i];
      #pragma unroll
      for (int i = 0; i < 8; ++i)
        *reinterpret_cast<bf16_t*>(&Vlds[swz(d0 + 8 + i, kv * 2)]) = v1[i];
    }
    __syncthreads();

    // S^T = mfma(A=K, B=Q[j])
    f32x4 s[2][4] = {};
    #pragma unroll
    for (int ks = 0; ks < 2; ++ks) {
      const int kb = (ks * 32 + g * 8) * 2;
      #pragma unroll
      for (int ct = 0; ct < 4; ++ct) {
        bf16x8 kf = *reinterpret_cast<const bf16x8*>(&Klds[swz(ct * 16 + qh, kb)]);
        s[0][ct] = mfma16(kf, qf[0][ks], s[0][ct]);
        s[1][ct] = mfma16(kf, qf[1][ks], s[1][ct]);
      }
    }

    #pragma unroll
    for (int j = 0; j < 2; ++j) {
      float rmax = -1e30f;
      #pragma unroll
      for (int ct = 0; ct < 4; ++ct) {
        #pragma unroll
        for (int r = 0; r < 4; ++r) {
          float x = ((mw[j] >> (ct * 16 + g * 4 + r)) & 1) ? s[j][ct][r] : -1e8f;
          s[j][ct][r] = x;
          rmax = fmaxf(rmax, x);
        }
      }
      rmax = fmaxf(rmax, __shfl_xor(rmax, 16));
      rmax = fmaxf(rmax, __shfl_xor(rmax, 32));
      const float newm = fmaxf(mrun[j], rmax);

      if (__any(newm > mrun[j])) {
        const float scale = __builtin_amdgcn_exp2f(mrun[j] - newm);
        lsum[j] *= scale;
        #pragma unroll
        for (int r = 0; r < 4; ++r) {
          const float sr = __shfl(scale, g * 4 + r, 64);
          #pragma unroll
          for (int dct = 0; dct < 4; ++dct) acc[j][dct][r] *= sr;
        }
        mrun[j] = newm;
      }

      float psum = 0.f;
      #pragma unroll
      for (int ct = 0; ct < 4; ++ct) {
        #pragma unroll
        for (int r = 0; r < 4; ++r) {
          const float pv = __builtin_amdgcn_exp2f(s[j][ct][r] - mrun[j]);
          s[j][ct][r] = pv;
          psum += pv;
        }
      }
      psum += __shfl_xor(psum, 16);
      psum += __shfl_xor(psum, 32);
      lsum[j] += psum;

      // P writes — SCALAR bf16 stores only (curse rule)
      #pragma unroll
      for (int ct = 0; ct < 4; ++ct) {
        #pragma unroll
        for (int r = 0; r < 4; ++r)
          *reinterpret_cast<bf16_t*>(
              &Pw[swz(j * 16 + qh, (ct * 16 + g * 4 + r) * 2)]) = (bf16_t)s[j][ct][r];
      }
    }

    // O += P V
    #pragma unroll
    for (int ks = 0; ks < 2; ++ks) {
      const int kb = (ks * 32 + g * 8) * 2;
      bf16x8 pf0 = *reinterpret_cast<const bf16x8*>(&Pw[swz(qh, kb)]);
      bf16x8 pf1 = *reinterpret_cast<const bf16x8*>(&Pw[swz(16 + qh, kb)]);
      #pragma unroll
      for (int dct = 0; dct < 4; ++dct) {
        bf16x8 vf = *reinterpret_cast<const bf16x8*>(&Vlds[swz(dct * 16 + qh, kb)]);
        acc[0][dct] = mfma16(pf0, vf, acc[0][dct]);
        acc[1][dct] = mfma16(pf1, vf, acc[1][dct]);
      }
    }
  }

  // ---- flash combine of the two kv-halves through LDS (K/V/P now dead) ----
  __syncthreads();
  float* creg = reinterpret_cast<float*>(SMEM + w4 * 9216);   // 36 fields x 64 lanes
  if (hw == 1) {
    creg[0 * 64 + l] = mrun[0];
    creg[1 * 64 + l] = mrun[1];
    creg[2 * 64 + l] = lsum[0];
    creg[3 * 64 + l] = lsum[1];
    #pragma unroll
    for (int j = 0; j < 2; ++j)
      #pragma unroll
      for (int dct = 0; dct < 4; ++dct)
        #pragma unroll
        for (int r = 0; r < 4; ++r)
          creg[(4 + j * 16 + dct * 4 + r) * 64 + l] = acc[j][dct][r];
  }
  __syncthreads();
  if (hw == 0) {
    #pragma unroll
    for (int j = 0; j < 2; ++j) {
      const float mb = creg[j * 64 + l];
      const float lb = creg[(2 + j) * 64 + l];
      const float m = fmaxf(mrun[j], mb);
      const float wa = __builtin_amdgcn_exp2f(mrun[j] - m);
      const float wb = __builtin_amdgcn_exp2f(mb - m);
      const float inv = 1.0f / (lsum[j] * wa + lb * wb);
      float war[4], wbr[4], invr[4];
      #pragma unroll
      for (int r = 0; r < 4; ++r) {
        war[r]  = __shfl(wa, g * 4 + r, 64);
        wbr[r]  = __shfl(wb, g * 4 + r, 64);
        invr[r] = __shfl(inv, g * 4 + r, 64);
      }
      #pragma unroll
      for (int dct = 0; dct < 4; ++dct) {
        const int col = h * DKH + dct * 16 + qh;
        #pragma unroll
        for (int r = 0; r < 4; ++r) {
          const float ob = creg[(4 + j * 16 + dct * 4 + r) * 64 + l];
          const int q = wq0 + j * 16 + g * 4 + r;
          AO[(rb + q) * DMODEL + col] =
              (bf16_t)((acc[j][dct][r] * war[r] + ob * wbr[r]) * invr[r]);
        }
      }
    }
  }
}

extern "C" void kernel_launch(void* const* d_in, const int* in_sizes, int n_in,
                              void* d_out, int out_size, void* d_ws, size_t ws_size,
                              hipStream_t stream)
{
  const float* query = (const float*)d_in[0];
  const float* keyin = (const float*)d_in[1];
  const int*   mask  = (const int*)d_in[2];
  const float* Wq = (const float*)d_in[3];
  const float* bq = (const float*)d_in[4];
  const float* Wk = (const float*)d_in[5];
  const float* bk = (const float*)d_in[6];
  const float* Wv = (const float*)d_in[7];
  const float* bv = (const float*)d_in[8];
  const float* Wo = (const float*)d_in[9];
  const float* bo = (const float*)d_in[10];
  float* out = (float*)d_out;

  bf16_t* Qp = (bf16_t*)d_ws;
  bf16_t* Kp = Qp + (size_t)MROWS * DMODEL;
  bf16_t* Vp = Kp + (size_t)MROWS * DMODEL;
  bf16_t* AO = Vp + (size_t)MROWS * DMODEL;
  unsigned long long* Mpk = (unsigned long long*)(AO + (size_t)MROWS * DMODEL);
  bf16_t* Wtq = (bf16_t*)(Mpk + MWORDS);
  bf16_t* Wtk = Wtq + 512 * 256;
  bf16_t* Wtv = Wtk + 512 * 256;
  bf16_t* Wto = Wtv + 512 * 256;

  dim3 blk(256);

  weight_prep<<<dim3(160), blk, 0, stream>>>(Wq, Wk, Wv, Wo, Wtq, Wtk, Wtv, Wto);
  mask_pack<<<dim3(MWORDS / 256), blk, 0, stream>>>(mask, Mpk);
  gemm_bias_act<256, true, float, bf16_t><<<dim3(1024), blk, 0, stream>>>(query, Wtq, bq, Qp, 1.0f);
  gemm_kv<<<dim3(1024), blk, 0, stream>>>(keyin, Wtk, Wtv, bk, bv, Kp, Vp);

  attn_kernel<<<dim3(NB * NH * (LQ / 128)), dim3(512), 0, stream>>>(Qp, Kp, Vp, Mpk, AO);

  gemm_bias_act<512, false, bf16_t, float><<<dim3(1024), blk, 0, stream>>>(AO, Wto, bo, out, 1.0f);
}

// Round 14
// 97.431 us; speedup vs baseline: 1.7485x; 1.0894x over previous
//
#include <hip/hip_runtime.h>
#include <hip/hip_bf16.h>
#include <type_traits>

typedef __bf16 bf16_t;
typedef __bf16 bf16x4 __attribute__((ext_vector_type(4)));
typedef __bf16 bf16x8 __attribute__((ext_vector_type(8)));
typedef float  f32x4  __attribute__((ext_vector_type(4)));

__device__ __forceinline__ f32x4 mfma16(bf16x8 a, bf16x8 b, f32x4 c) {
  return __builtin_amdgcn_mfma_f32_16x16x32_bf16(a, b, c, 0, 0, 0);
}

static constexpr int NB = 8;
static constexpr int LQ = 1024;
static constexpr int LKk = 1024;
static constexpr int DMODEL = 512;
static constexpr int NH = 8;
static constexpr int DKH = 64;
static constexpr int MROWS = NB * LQ;   // 8192
static constexpr int MWORDS = NB * LQ * (LKk / 64);  // 131072 u64 words
// K prescale: 1/sqrt(64) folded with 1/ln(2) for exp2-domain softmax
#define KSCALE 0.1803368801111204f

// swizzled byte offset for [R][128B] row-major LDS tiles (G4 XOR swizzle)
__device__ __forceinline__ int swz(int row, int byte) {
  return row * 128 + (byte ^ ((row & 7) << 4));
}

// ------- mask bit-pack: one u64 word per THREAD, 16 independent int4 loads --
__global__ __launch_bounds__(256)
void mask_pack(const int* __restrict__ mask, unsigned long long* __restrict__ mpk) {
  const int wd = blockIdx.x * 256 + threadIdx.x;
  const int4* base = reinterpret_cast<const int4*>(mask + (size_t)wd * 64);
  unsigned long long bits = 0;
  #pragma unroll
  for (int i = 0; i < 16; ++i) {
    int4 v = base[i];
    bits |= (unsigned long long)(v.x != 0) << (4 * i);
    bits |= (unsigned long long)(v.y != 0) << (4 * i + 1);
    bits |= (unsigned long long)(v.z != 0) << (4 * i + 2);
    bits |= (unsigned long long)(v.w != 0) << (4 * i + 3);
  }
  mpk[wd] = bits;
}

// ------- one-time weight transpose+convert: W f32 [K][N] -> Wt bf16 [N][K] --
__device__ __forceinline__ void wt_tile(const float* __restrict__ W, bf16_t* __restrict__ Wt,
                                        int K, int N, int kt, int nt, int t) {
  __shared__ bf16_t T[64][72];
  const int k0 = kt * 64, n0 = nt * 64;
  const int kr = t >> 2, c0 = (t & 3) * 16;
  const float4* src = reinterpret_cast<const float4*>(W + (size_t)(k0 + kr) * N + n0 + c0);
  #pragma unroll
  for (int j = 0; j < 4; ++j) {
    float4 f = src[j];
    T[c0 + j * 4 + 0][kr] = (bf16_t)f.x;
    T[c0 + j * 4 + 1][kr] = (bf16_t)f.y;
    T[c0 + j * 4 + 2][kr] = (bf16_t)f.z;
    T[c0 + j * 4 + 3][kr] = (bf16_t)f.w;
  }
  __syncthreads();
  const int nr = t >> 2, kc0 = (t & 3) * 16;
  bf16_t* dst = Wt + (size_t)(n0 + nr) * K + k0 + kc0;
  #pragma unroll
  for (int j = 0; j < 2; ++j)
    *reinterpret_cast<bf16x8*>(dst + j * 8) =
        *reinterpret_cast<const bf16x8*>(&T[nr][kc0 + j * 8]);
}

__global__ __launch_bounds__(256)
void weight_prep(const float* __restrict__ Wq, const float* __restrict__ Wk,
                 const float* __restrict__ Wv, const float* __restrict__ Wo,
                 bf16_t* __restrict__ Wtq, bf16_t* __restrict__ Wtk,
                 bf16_t* __restrict__ Wtv, bf16_t* __restrict__ Wto) {
  const int bidx = blockIdx.x, t = threadIdx.x;
  if (bidx < 32)        wt_tile(Wq, Wtq, 256, 512, bidx >> 3, bidx & 7, t);
  else if (bidx < 64)   wt_tile(Wk, Wtk, 256, 512, (bidx - 32) >> 3, bidx & 7, t);
  else if (bidx < 96)   wt_tile(Wv, Wtv, 256, 512, (bidx - 64) >> 3, bidx & 7, t);
  else                  wt_tile(Wo, Wto, 512, 512, (bidx - 96) >> 3, bidx & 7, t);
}

// C[M,512] = postscale * act(A @ Wt^T + bias); single-output (Q, out-proj)
template<int K, bool RELU, typename AT, typename OT>
__global__ __launch_bounds__(256)
void gemm_bias_act(const AT* __restrict__ A, const bf16_t* __restrict__ Wt,
                   const float* __restrict__ bias, OT* __restrict__ C,
                   float postscale)
{
  constexpr int N = 512;
  __shared__ alignas(16) char Alds[64 * 128];
  __shared__ alignas(16) char Wlds[64 * 128];
  const int t = threadIdx.x;
  const int l = t & 63, w = t >> 6;
  const int xcd = blockIdx.x & 7, idx = blockIdx.x >> 3;
  const int m0 = (xcd * 16 + (idx >> 3)) * 64, n0 = (idx & 7) * 64;

  f32x4 acc[4] = {};
  for (int k0 = 0; k0 < K; k0 += 64) {
    __syncthreads();
    if constexpr (std::is_same<AT, float>::value) {
      const int row = t >> 2, c0 = (t & 3) * 16;
      const float4* ap = reinterpret_cast<const float4*>(A + (size_t)(m0 + row) * K + k0 + c0);
      #pragma unroll
      for (int j = 0; j < 4; ++j) {
        float4 f = ap[j];
        bf16x4 o = { (bf16_t)f.x, (bf16_t)f.y, (bf16_t)f.z, (bf16_t)f.w };
        *reinterpret_cast<bf16x4*>(&Alds[swz(row, (c0 + j * 4) * 2)]) = o;
      }
    } else {
      const int row = t >> 2, cb = ((2 * t) & 7) * 16;
      const bf16_t* src = A + (size_t)(m0 + row) * K + k0 + cb / 2;
      *reinterpret_cast<bf16x8*>(&Alds[swz(row, cb)]) = *reinterpret_cast<const bf16x8*>(src);
      *reinterpret_cast<bf16x8*>(&Alds[swz(row, cb + 16)]) = *reinterpret_cast<const bf16x8*>(src + 8);
    }
    {
      const int row = t >> 2, cb = ((2 * t) & 7) * 16;
      const bf16_t* src = Wt + (size_t)(n0 + row) * K + k0 + cb / 2;
      *reinterpret_cast<bf16x8*>(&Wlds[swz(row, cb)]) = *reinterpret_cast<const bf16x8*>(src);
      *reinterpret_cast<bf16x8*>(&Wlds[swz(row, cb + 16)]) = *reinterpret_cast<const bf16x8*>(src + 8);
    }
    __syncthreads();
    #pragma unroll
    for (int ks = 0; ks < 2; ++ks) {
      const int kb = (ks * 32 + ((l >> 4) * 8)) * 2;
      const int arow = w * 16 + (l & 15);
      bf16x8 af = *reinterpret_cast<const bf16x8*>(&Alds[swz(arow, kb)]);
      #pragma unroll
      for (int ct = 0; ct < 4; ++ct) {
        const int brow = ct * 16 + (l & 15);
        bf16x8 bfr = *reinterpret_cast<const bf16x8*>(&Wlds[swz(brow, kb)]);
        acc[ct] = mfma16(af, bfr, acc[ct]);
      }
    }
  }
  #pragma unroll
  for (int ct = 0; ct < 4; ++ct) {
    const int col = n0 + ct * 16 + (l & 15);
    const float bv = bias[col];
    #pragma unroll
    for (int r = 0; r < 4; ++r) {
      const int row = m0 + w * 16 + ((l >> 4) * 4) + r;
      float x = acc[ct][r] + bv;
      if constexpr (RELU) x = fmaxf(x, 0.f);
      C[(size_t)row * N + col] = (OT)(x * postscale);
    }
  }
}

// ------- merged K+V projection; V written TRANSPOSED [b][h][d][kv] ----------
__global__ __launch_bounds__(256)
void gemm_kv(const float* __restrict__ A, const bf16_t* __restrict__ Wtk,
             const bf16_t* __restrict__ Wtv, const float* __restrict__ bk,
             const float* __restrict__ bv, bf16_t* __restrict__ Ck,
             bf16_t* __restrict__ Vt)
{
  constexpr int K = 256, N = 512;
  __shared__ alignas(16) char Alds[64 * 128];
  __shared__ alignas(16) char Wk_lds[64 * 128];
  __shared__ alignas(16) char Wv_lds[64 * 128];
  const int t = threadIdx.x;
  const int l = t & 63, w = t >> 6;
  const int xcd = blockIdx.x & 7, idx = blockIdx.x >> 3;
  const int m0 = (xcd * 16 + (idx >> 3)) * 64, n0 = (idx & 7) * 64;

  f32x4 acck[4] = {}, accv[4] = {};
  for (int k0 = 0; k0 < K; k0 += 64) {
    __syncthreads();
    {
      const int row = t >> 2, c0 = (t & 3) * 16;
      const float4* ap = reinterpret_cast<const float4*>(A + (size_t)(m0 + row) * K + k0 + c0);
      #pragma unroll
      for (int j = 0; j < 4; ++j) {
        float4 f = ap[j];
        bf16x4 o = { (bf16_t)f.x, (bf16_t)f.y, (bf16_t)f.z, (bf16_t)f.w };
        *reinterpret_cast<bf16x4*>(&Alds[swz(row, (c0 + j * 4) * 2)]) = o;
      }
    }
    {
      const int row = t >> 2, cb = ((2 * t) & 7) * 16;
      const bf16_t* sk = Wtk + (size_t)(n0 + row) * K + k0 + cb / 2;
      const bf16_t* sv = Wtv + (size_t)(n0 + row) * K + k0 + cb / 2;
      *reinterpret_cast<bf16x8*>(&Wk_lds[swz(row, cb)]) = *reinterpret_cast<const bf16x8*>(sk);
      *reinterpret_cast<bf16x8*>(&Wk_lds[swz(row, cb + 16)]) = *reinterpret_cast<const bf16x8*>(sk + 8);
      *reinterpret_cast<bf16x8*>(&Wv_lds[swz(row, cb)]) = *reinterpret_cast<const bf16x8*>(sv);
      *reinterpret_cast<bf16x8*>(&Wv_lds[swz(row, cb + 16)]) = *reinterpret_cast<const bf16x8*>(sv + 8);
    }
    __syncthreads();
    #pragma unroll
    for (int ks = 0; ks < 2; ++ks) {
      const int kb = (ks * 32 + ((l >> 4) * 8)) * 2;
      const int arow = w * 16 + (l & 15);
      bf16x8 af = *reinterpret_cast<const bf16x8*>(&Alds[swz(arow, kb)]);
      #pragma unroll
      for (int ct = 0; ct < 4; ++ct) {
        const int brow = ct * 16 + (l & 15);
        bf16x8 bk8 = *reinterpret_cast<const bf16x8*>(&Wk_lds[swz(brow, kb)]);
        bf16x8 bv8 = *reinterpret_cast<const bf16x8*>(&Wv_lds[swz(brow, kb)]);
        acck[ct] = mfma16(af, bk8, acck[ct]);
        accv[ct] = mfma16(af, bv8, accv[ct]);
      }
    }
  }
  const int row0 = m0 + w * 16 + ((l >> 4) * 4);   // 4 consecutive kv rows
  const int vb = row0 >> 10;                       // batch
  const int kv = row0 & 1023;
  #pragma unroll
  for (int ct = 0; ct < 4; ++ct) {
    const int col = n0 + ct * 16 + (l & 15);
    const float bkv = bk[col], bvv = bv[col];
    #pragma unroll
    for (int r = 0; r < 4; ++r)
      Ck[(size_t)(row0 + r) * N + col] = (bf16_t)(fmaxf(acck[ct][r] + bkv, 0.f) * KSCALE);
    bf16x4 vv;
    #pragma unroll
    for (int r = 0; r < 4; ++r) vv[r] = (bf16_t)fmaxf(accv[ct][r] + bvv, 0.f);
    // Vt[((vb*8 + col>>6)*64 + col&63)][kv..kv+3]  (8B aligned: kv % 4 == 0)
    bf16_t* dst = Vt + (((size_t)vb * NH + (col >> 6)) * DKH + (col & 63)) * LKk + kv;
    *reinterpret_cast<bf16x4*>(dst) = vv;
  }
}

// -- flash attention: R11-verified structure (4 waves, QBLK=32); V staged from
//    pre-transposed Vt via the K-staging vector pattern (no in-kernel transpose)
__global__ __launch_bounds__(256)
void attn_kernel(const bf16_t* __restrict__ Qp, const bf16_t* __restrict__ Kp,
                 const bf16_t* __restrict__ Vt, const unsigned long long* __restrict__ Mpk,
                 bf16_t* __restrict__ AO)
{
  __shared__ alignas(16) char Klds[64 * 128];       // [kv][d] row-major, swizzled
  __shared__ alignas(16) char Vlds[64 * 128];       // [d][kv] rows, swizzled
  __shared__ alignas(16) char Plds[4 * 32 * 128];   // per-wave [32 q][64 kv], swizzled
  const int t = threadIdx.x, l = t & 63, w = t >> 6;
  const int g = l >> 4, qh = l & 15;
  const int bid = (blockIdx.x & 7) * 64 + (blockIdx.x >> 3);
  const int qt = bid & 7, h = (bid >> 3) & 7, b = bid >> 6;
  const int wq0 = qt * 128 + w * 32;
  const size_t rb = (size_t)b * LQ;
  const bf16_t* vtb = Vt + ((size_t)b * NH + h) * DKH * LKk;   // [d][kv] for (b,h)

  bf16x8 qf[2][2];
  #pragma unroll
  for (int j = 0; j < 2; ++j)
    #pragma unroll
    for (int ks = 0; ks < 2; ++ks)
      qf[j][ks] = *reinterpret_cast<const bf16x8*>(
          Qp + (rb + wq0 + j * 16 + qh) * DMODEL + h * DKH + ks * 32 + g * 8);

  const unsigned long long* mrow0 = Mpk + (rb + wq0 + qh) * (LKk / 64);
  const unsigned long long* mrow1 = Mpk + (rb + wq0 + 16 + qh) * (LKk / 64);

  f32x4 acc[2][4] = {};
  float mrun[2] = { -1e30f, -1e30f }, lsum[2] = { 0.f, 0.f };

  for (int kv0 = 0; kv0 < LKk; kv0 += 64) {
    const unsigned long long mw[2] = { mrow0[kv0 >> 6], mrow1[kv0 >> 6] };

    __syncthreads();
    // stage K tile [64 kv][64 d] — R9-proven vector pattern
    {
      const int row = t >> 2, cb = ((2 * t) & 7) * 16;
      const bf16_t* src = Kp + (rb + kv0 + row) * DMODEL + h * DKH + cb / 2;
      *reinterpret_cast<bf16x8*>(&Klds[swz(row, cb)]) = *reinterpret_cast<const bf16x8*>(src);
      *reinterpret_cast<bf16x8*>(&Klds[swz(row, cb + 16)]) = *reinterpret_cast<const bf16x8*>(src + 8);
    }
    // stage V tile [64 d][64 kv] from pre-transposed Vt — same vector pattern
    {
      const int row = t >> 2, cb = ((2 * t) & 7) * 16;
      const bf16_t* src = vtb + (size_t)row * LKk + kv0 + cb / 2;
      *reinterpret_cast<bf16x8*>(&Vlds[swz(row, cb)]) = *reinterpret_cast<const bf16x8*>(src);
      *reinterpret_cast<bf16x8*>(&Vlds[swz(row, cb + 16)]) = *reinterpret_cast<const bf16x8*>(src + 8);
    }
    __syncthreads();

    // S^T = mfma(A=K, B=Q[j]): each K-frag read feeds both q-groups
    f32x4 s[2][4] = {};
    #pragma unroll
    for (int ks = 0; ks < 2; ++ks) {
      const int kb = (ks * 32 + g * 8) * 2;
      #pragma unroll
      for (int ct = 0; ct < 4; ++ct) {
        bf16x8 kf = *reinterpret_cast<const bf16x8*>(&Klds[swz(ct * 16 + qh, kb)]);
        s[0][ct] = mfma16(kf, qf[0][ks], s[0][ct]);
        s[1][ct] = mfma16(kf, qf[1][ks], s[1][ct]);
      }
    }

    #pragma unroll
    for (int j = 0; j < 2; ++j) {
      float rmax = -1e30f;
      #pragma unroll
      for (int ct = 0; ct < 4; ++ct) {
        #pragma unroll
        for (int r = 0; r < 4; ++r) {
          float x = ((mw[j] >> (ct * 16 + g * 4 + r)) & 1) ? s[j][ct][r] : -1e8f;
          s[j][ct][r] = x;
          rmax = fmaxf(rmax, x);
        }
      }
      rmax = fmaxf(rmax, __shfl_xor(rmax, 16));
      rmax = fmaxf(rmax, __shfl_xor(rmax, 32));
      const float newm = fmaxf(mrun[j], rmax);

      if (__any(newm > mrun[j])) {
        const float scale = __builtin_amdgcn_exp2f(mrun[j] - newm);
        lsum[j] *= scale;
        #pragma unroll
        for (int r = 0; r < 4; ++r) {
          const float sr = __shfl(scale, g * 4 + r, 64);
          #pragma unroll
          for (int dct = 0; dct < 4; ++dct) acc[j][dct][r] *= sr;
        }
        mrun[j] = newm;
      }

      float psum = 0.f;
      #pragma unroll
      for (int ct = 0; ct < 4; ++ct) {
        #pragma unroll
        for (int r = 0; r < 4; ++r) {
          const float pv = __builtin_amdgcn_exp2f(s[j][ct][r] - mrun[j]);
          s[j][ct][r] = pv;
          psum += pv;
        }
      }
      psum += __shfl_xor(psum, 16);
      psum += __shfl_xor(psum, 32);
      lsum[j] += psum;

      // P writes — SCALAR bf16 stores only (curse rule)
      #pragma unroll
      for (int ct = 0; ct < 4; ++ct) {
        #pragma unroll
        for (int r = 0; r < 4; ++r)
          *reinterpret_cast<bf16_t*>(
              &Plds[w * 4096 + swz(j * 16 + qh, (ct * 16 + g * 4 + r) * 2)]) =
              (bf16_t)s[j][ct][r];
      }
    }

    // O += P V: each V-frag read feeds both q-groups
    #pragma unroll
    for (int ks = 0; ks < 2; ++ks) {
      const int kb = (ks * 32 + g * 8) * 2;
      bf16x8 pf0 = *reinterpret_cast<const bf16x8*>(&Plds[w * 4096 + swz(qh, kb)]);
      bf16x8 pf1 = *reinterpret_cast<const bf16x8*>(&Plds[w * 4096 + swz(16 + qh, kb)]);
      #pragma unroll
      for (int dct = 0; dct < 4; ++dct) {
        bf16x8 vf = *reinterpret_cast<const bf16x8*>(&Vlds[swz(dct * 16 + qh, kb)]);
        acc[0][dct] = mfma16(pf0, vf, acc[0][dct]);
        acc[1][dct] = mfma16(pf1, vf, acc[1][dct]);
      }
    }
  }

  #pragma unroll
  for (int j = 0; j < 2; ++j) {
    const float inv = 1.0f / lsum[j];
    float invr[4];
    #pragma unroll
    for (int r = 0; r < 4; ++r) invr[r] = __shfl(inv, g * 4 + r, 64);
    #pragma unroll
    for (int dct = 0; dct < 4; ++dct) {
      const int col = h * DKH + dct * 16 + qh;
      #pragma unroll
      for (int r = 0; r < 4; ++r) {
        const int q = wq0 + j * 16 + g * 4 + r;
        AO[(rb + q) * DMODEL + col] = (bf16_t)(acc[j][dct][r] * invr[r]);
      }
    }
  }
}

extern "C" void kernel_launch(void* const* d_in, const int* in_sizes, int n_in,
                              void* d_out, int out_size, void* d_ws, size_t ws_size,
                              hipStream_t stream)
{
  const float* query = (const float*)d_in[0];
  const float* keyin = (const float*)d_in[1];
  const int*   mask  = (const int*)d_in[2];
  const float* Wq = (const float*)d_in[3];
  const float* bq = (const float*)d_in[4];
  const float* Wk = (const float*)d_in[5];
  const float* bk = (const float*)d_in[6];
  const float* Wv = (const float*)d_in[7];
  const float* bv = (const float*)d_in[8];
  const float* Wo = (const float*)d_in[9];
  const float* bo = (const float*)d_in[10];
  float* out = (float*)d_out;

  bf16_t* Qp = (bf16_t*)d_ws;
  bf16_t* Kp = Qp + (size_t)MROWS * DMODEL;
  bf16_t* Vt = Kp + (size_t)MROWS * DMODEL;   // [b][h][d][kv], same 8MB footprint
  bf16_t* AO = Vt + (size_t)MROWS * DMODEL;
  unsigned long long* Mpk = (unsigned long long*)(AO + (size_t)MROWS * DMODEL);
  bf16_t* Wtq = (bf16_t*)(Mpk + MWORDS);
  bf16_t* Wtk = Wtq + 512 * 256;
  bf16_t* Wtv = Wtk + 512 * 256;
  bf16_t* Wto = Wtv + 512 * 256;

  dim3 blk(256);

  weight_prep<<<dim3(160), blk, 0, stream>>>(Wq, Wk, Wv, Wo, Wtq, Wtk, Wtv, Wto);
  mask_pack<<<dim3(MWORDS / 256), blk, 0, stream>>>(mask, Mpk);
  gemm_bias_act<256, true, float, bf16_t><<<dim3(1024), blk, 0, stream>>>(query, Wtq, bq, Qp, 1.0f);
  gemm_kv<<<dim3(1024), blk, 0, stream>>>(keyin, Wtk, Wtv, bk, bv, Kp, Vt);

  attn_kernel<<<dim3(NB * NH * (LQ / 128)), blk, 0, stream>>>(Qp, Kp, Vt, Mpk, AO);

  gemm_bias_act<512, false, bf16_t, float><<<dim3(1024), blk, 0, stream>>>(AO, Wto, bo, out, 1.0f);
}